// Round 2
// baseline (297.178 us; speedup 1.0000x reference)
//
#include <hip/hip_runtime.h>
#include <hip/hip_bf16.h>
#include <math.h>

// Sizes (fixed by the problem)
#define BATCH 16
#define TLEN  512
#define HD    16     // per-direction hidden
#define HID   32     // 2*HD

typedef float v2f __attribute__((ext_vector_type(2)));

// Static device scratch — avoids any assumption about ws_size.
// All arrays fully written before read each call; g_cnt/g_accum are zero-init
// .bss and restored to 0 by the last-arriver block each call.
__device__ float g_outBT[BATCH * TLEN * HID];   // 1 MB
__device__ float g_preA [BATCH * TLEN * HID];   // 1 MB
__device__ float g_Ct   [BATCH * HID * TLEN];   // 1 MB
__device__ float g_un   [BATCH * TLEN];
__device__ float g_w2d  [BATCH * TLEN];
__device__ float g_accum[BATCH];                // zero-initialized, self-resetting
__device__ int   g_cnt  [BATCH];                // zero-initialized, self-resetting

__device__ __forceinline__ float sigm_(float x) {
    return 1.0f / (1.0f + __expf(-x));
}
__device__ __forceinline__ float tanh_(float x) {
    float e = __expf(2.0f * x);
    return 1.0f - 2.0f / (e + 1.0f);
}

__device__ __forceinline__ v2f pk_fma(v2f a, v2f b, v2f c) {
#if __has_builtin(__builtin_elementwise_fma)
    return __builtin_elementwise_fma(a, b, c);   // -> v_pk_fma_f32
#else
    v2f r; r.x = fmaf(a.x, b.x, c.x); r.y = fmaf(a.y, b.y, c.y); return r;
#endif
}

// ---------------------------------------------------------------------------
// K1: bidirectional LSTM, round 8.
// Rounds 6/7 post-mortem: VGPR_Count = 52 / 40 respectively — in BOTH cases
// smaller than the weight working set, while `volatile` forbids re-loading.
// Conclusion: the v2f weight ARRAYS were demoted to scratch and re-read every
// timestep (~600 stall cyc/step; per-CU VALUBusy only ~16%). Round 7's
// ds_swizzle half-combine also put ~120 cyc of LDS-crossbar latency on the
// serial chain and was net slower.
// This version:
//  - 8 blocks x 64 threads, 4 chains/wave (dir = blk>>2, b = (blk&3)*4 + q,
//    lane = (q = lane>>4, u = lane&15)). Full 16-term recurrent dot per lane:
//    NO cross-lane combine on the critical path.
//  - Weights in INDIVIDUALLY NAMED v2f variables (no arrays, no volatile):
//    nothing for the allocator to demote. ~110 live VGPRs, budget is 512
//    (__launch_bounds__(64,1)). VGPR_Count >= ~96 is the success signal.
//  - 15 INDEPENDENT DPP row_ror:k rotations (k=1..15) all sourced from the
//    same hn base — no serial rotate chain.
//  - 2 accumulator pairs -> fma dep depth 8.
// ---------------------------------------------------------------------------
__global__ __launch_bounds__(64, 1) void k1_lstm(
    const float* __restrict__ sent,   // [B,T]
    const float* __restrict__ h0,     // [2,B,16]
    const float* __restrict__ c0,     // [2,B,16]
    const float* __restrict__ Wih_f, const float* __restrict__ Whh_f, const float* __restrict__ b_f,
    const float* __restrict__ Wih_b, const float* __restrict__ Whh_b, const float* __restrict__ b_b)
{
    const int blk  = blockIdx.x;      // 0..7
    const int dir  = blk >> 2;        // 0 fwd, 1 bwd
    const int bg   = blk & 3;         // batch group of 4
    const int lane = threadIdx.x;
    const int q    = lane >> 4;       // batch slot in wave
    const int u    = lane & 15;       // hidden unit
    const int b    = bg * 4 + q;

    const float* Wih  = dir ? Wih_b : Wih_f;
    const float* Whh  = dir ? Whh_b : Whh_f;
    const float* bias = dir ? b_b   : b_f;

    // Pre-rotated gate rows for unit u (torch order i,f,g,o at u,+16,+32,+48):
    // wIF<k>/wGO<k> multiply h[(u-k)&15] (delivered by row_ror:k).
    // Individually named so they CANNOT be demoted to scratch.
    v2f wIF0, wIF1, wIF2, wIF3, wIF4, wIF5, wIF6, wIF7,
        wIF8, wIF9, wIF10, wIF11, wIF12, wIF13, wIF14, wIF15;
    v2f wGO0, wGO1, wGO2, wGO3, wGO4, wGO5, wGO6, wGO7,
        wGO8, wGO9, wGO10, wGO11, wGO12, wGO13, wGO14, wGO15;
#define LDW(K) { const int m = (u - (K)) & 15;            \
        wIF##K.x = Whh[(u)      * 16 + m];                \
        wIF##K.y = Whh[(u + 16) * 16 + m];                \
        wGO##K.x = Whh[(u + 32) * 16 + m];                \
        wGO##K.y = Whh[(u + 48) * 16 + m]; }
    LDW(0)  LDW(1)  LDW(2)  LDW(3)  LDW(4)  LDW(5)  LDW(6)  LDW(7)
    LDW(8)  LDW(9)  LDW(10) LDW(11) LDW(12) LDW(13) LDW(14) LDW(15)
#undef LDW

    v2f wxIF, wxGO, bIF2, bGO2;
    wxIF.x = Wih[u];      wxIF.y = Wih[u + 16];
    wxGO.x = Wih[u + 32]; wxGO.y = Wih[u + 48];
    bIF2.x = bias[u];      bIF2.y = bias[u + 16];
    bGO2.x = bias[u + 32]; bGO2.y = bias[u + 48];

    // per-lane state: this lane's own h (unit u) and c
    float hn = h0[dir * (BATCH * HD) + b * HD + u];
    float c  = c0[dir * (BATCH * HD) + b * HD + u];

    const float* srow = sent + b * TLEN;
    float* obase = g_outBT + (size_t)b * TLEN * HID + dir * HD + u;

    // double-buffered x chunk (4 steps per chunk); bwd consumes reversed
    float4 xc = *(const float4*)(srow + (dir ? (TLEN - 4) : 0));
    for (int tb = 0; tb < TLEN; tb += 4) {
        float4 xn = xc;
        if (tb + 4 < TLEN)
            xn = *(const float4*)(srow + (dir ? (TLEN - 8 - tb) : (tb + 4)));
        float xa[4];
        if (dir) { xa[0] = xc.w; xa[1] = xc.z; xa[2] = xc.y; xa[3] = xc.x; }
        else     { xa[0] = xc.x; xa[1] = xc.y; xa[2] = xc.z; xa[3] = xc.w; }

        #pragma unroll
        for (int s2 = 0; s2 < 4; ++s2) {
            const int t   = tb + s2;
            const int pos = dir ? (TLEN - 1 - t) : t;
            const float x = xa[s2];

            v2f xv; xv.x = x; xv.y = x;
            v2f aIF0 = pk_fma(xv, wxIF, bIF2);
            v2f aGO0 = pk_fma(xv, wxGO, bGO2);
            v2f aIF1; aIF1.x = 0.f; aIF1.y = 0.f;
            v2f aGO1; aGO1.x = 0.f; aGO1.y = 0.f;

            const int r0 = __float_as_int(hn);

            // k=0: own h, no rotation
            { v2f hv; hv.x = hn; hv.y = hn;
              aIF0 = pk_fma(wIF0, hv, aIF0);
              aGO0 = pk_fma(wGO0, hv, aGO0); }

            // k=1..15: INDEPENDENT rotations, all sourced from r0
#define ACCA(K) { v2f hv;                                                        \
        hv.x = __int_as_float(__builtin_amdgcn_mov_dpp(r0, 0x120 + K, 0xF, 0xF, true)); \
        hv.y = hv.x;                                                             \
        aIF0 = pk_fma(wIF##K, hv, aIF0);                                         \
        aGO0 = pk_fma(wGO##K, hv, aGO0); }
#define ACCB(K) { v2f hv;                                                        \
        hv.x = __int_as_float(__builtin_amdgcn_mov_dpp(r0, 0x120 + K, 0xF, 0xF, true)); \
        hv.y = hv.x;                                                             \
        aIF1 = pk_fma(wIF##K, hv, aIF1);                                         \
        aGO1 = pk_fma(wGO##K, hv, aGO1); }
            ACCB(1)  ACCA(2)  ACCB(3)  ACCA(4)  ACCB(5)  ACCA(6)  ACCB(7)
            ACCA(8)  ACCB(9)  ACCA(10) ACCB(11) ACCA(12) ACCB(13) ACCA(14) ACCB(15)
#undef ACCA
#undef ACCB

            v2f pIF = aIF0 + aIF1;
            v2f pGO = aGO0 + aGO1;

            const float ai = sigm_(pIF.x), af = sigm_(pIF.y), ao = sigm_(pGO.y);
            const float ag = tanh_(pGO.x);
            c = fmaf(af, c, ai * ag);
            hn = ao * tanh_(c);

            obase[(size_t)pos * HID] = hn;
        }
        xc = xn;
    }
}

// ---------------------------------------------------------------------------
// K2: projections. Thread per (b,t). W1 etc. staged in LDS.
//   preA[b][t][h] = out[b,t,:] . W1[h,0:32]  + b1[h]
//   Ct  [b][h][t] = out[b,t,:] . W1[h,32:64]           (transposed for K34)
//   un  [b][t]    = out . Wu + bu
//   w2d [b][t]    = out . Wout
// ---------------------------------------------------------------------------
__global__ __launch_bounds__(256) void k2_proj(
    const float* __restrict__ W1,     // [32,64]
    const float* __restrict__ b1,     // [32]
    const float* __restrict__ Wu,     // [32]
    const float* __restrict__ bu,     // [1]
    const float* __restrict__ Wout)   // [32]
{
    __shared__ float w1s[HID * 64];
    __shared__ float b1s[HID], wus[HID], wos[HID];
    const int tid = threadIdx.x;
    for (int k = tid; k < HID * 64; k += 256) w1s[k] = W1[k];
    if (tid < HID) { b1s[tid] = b1[tid]; wus[tid] = Wu[tid]; wos[tid] = Wout[tid]; }
    __syncthreads();

    const int g = blockIdx.x * 256 + tid;    // 0..8191
    const int b = g >> 9;
    const int t = g & (TLEN - 1);

    float o[32];
    const float4* src = (const float4*)(g_outBT + (size_t)g * HID);
    #pragma unroll
    for (int qq = 0; qq < 8; ++qq) {
        float4 v = src[qq];
        o[qq * 4 + 0] = v.x; o[qq * 4 + 1] = v.y; o[qq * 4 + 2] = v.z; o[qq * 4 + 3] = v.w;
    }

    float* pa = g_preA + (size_t)g * HID;
    float* ct = g_Ct + (size_t)b * HID * TLEN + t;
    #pragma unroll 4
    for (int h = 0; h < HID; ++h) {
        float a = b1s[h], cacc = 0.f;
        const float* wr = &w1s[h * 64];
        #pragma unroll
        for (int k = 0; k < HID; ++k) {
            a    = fmaf(o[k], wr[k], a);
            cacc = fmaf(o[k], wr[32 + k], cacc);
        }
        pa[h] = a;
        ct[(size_t)h * TLEN] = cacc;
    }

    float ua = 0.f, wa = 0.f;
    #pragma unroll
    for (int k = 0; k < HID; ++k) { ua = fmaf(o[k], wus[k], ua); wa = fmaf(o[k], wos[k], wa); }
    g_un[g]  = ua + bu[0];
    g_w2d[g] = wa;
}

// ---------------------------------------------------------------------------
// K34: S[b,i] = sum_j sum_h relu(preA[b,i,h] + Ct[b,h,j]) * W2[h]
//      prob[b,i] = sigmoid((S - diag_i + 511*b2)/100 + un[b,i])
//      out[b] = sum_i prob[b,i]*w2d[b,i] / 512 + bout   (fused, O(1)-atomic tail)
// ---------------------------------------------------------------------------
__global__ __launch_bounds__(256) void k34_binary(
    const float* __restrict__ W2,     // [32]
    const float* __restrict__ b2p,    // [1]
    const float* __restrict__ boutp,  // [1]
    float* __restrict__ out)          // [16]
{
    const int b     = blockIdx.x >> 6;
    const int itile = blockIdx.x & 63;
    const int i0    = itile * 8;
    const int tid   = threadIdx.x;

    __shared__ float pa[8][HID];
    __shared__ float w2s[HID];
    __shared__ float redw[4][8];

    pa[tid >> 5][tid & 31] = g_preA[((size_t)b * TLEN + i0 + (tid >> 5)) * HID + (tid & 31)];
    if (tid < HID) w2s[tid] = W2[tid];
    __syncthreads();

    const float* ctb = g_Ct + (size_t)b * HID * TLEN;
    const int j0 = tid, j1 = tid + 256;

    float acc[8];
    #pragma unroll
    for (int ii = 0; ii < 8; ++ii) acc[ii] = 0.f;

    for (int h = 0; h < HID; ++h) {
        const float c0v = ctb[(size_t)h * TLEN + j0];
        const float c1v = ctb[(size_t)h * TLEN + j1];
        const float w   = w2s[h];
        #pragma unroll
        for (int ii = 0; ii < 8; ++ii) {
            const float p = pa[ii][h];
            acc[ii] = fmaf(fmaxf(p + c0v, 0.f), w, acc[ii]);
            acc[ii] = fmaf(fmaxf(p + c1v, 0.f), w, acc[ii]);
        }
    }

    #pragma unroll
    for (int ii = 0; ii < 8; ++ii) {
        float v = acc[ii];
        #pragma unroll
        for (int off = 32; off >= 1; off >>= 1) v += __shfl_down(v, off);
        if ((tid & 63) == 0) redw[tid >> 6][ii] = v;
    }
    __syncthreads();

    if (tid < 8) {
        const float S = redw[0][tid] + redw[1][tid] + redw[2][tid] + redw[3][tid];
        const int i = i0 + tid;
        float diag = 0.f;
        #pragma unroll
        for (int h = 0; h < HID; ++h)
            diag = fmaf(fmaxf(pa[tid][h] + ctb[(size_t)h * TLEN + i], 0.f), w2s[h], diag);
        const float b2 = b2p[0];
        const float s = (S - diag + (float)(TLEN - 1) * b2) * 0.01f + g_un[(size_t)b * TLEN + i];
        float contrib = sigm_(s) * g_w2d[(size_t)b * TLEN + i];
        // reduce 8 lanes (lanes 0..7 of wave 0)
        contrib += __shfl_down(contrib, 4);
        contrib += __shfl_down(contrib, 2);
        contrib += __shfl_down(contrib, 1);
        if (tid == 0) {
            atomicAdd(&g_accum[b], contrib);          // one device-scope atomic
            __threadfence();
            int old = atomicAdd(&g_cnt[b], 1);
            if (old == 63) {                          // last arriver for this b
                __threadfence();
                float tot = atomicExch(&g_accum[b], 0.0f);  // read + reset
                out[b] = tot * (1.0f / (float)TLEN) + boutp[0];
                atomicExch(&g_cnt[b], 0);             // restore for next call
            }
        }
    }
}

extern "C" void kernel_launch(void* const* d_in, const int* in_sizes, int n_in,
                              void* d_out, int out_size, void* d_ws, size_t ws_size,
                              hipStream_t stream) {
    const float* sent  = (const float*)d_in[0];
    const float* h0    = (const float*)d_in[1];
    const float* c0    = (const float*)d_in[2];
    const float* Wih_f = (const float*)d_in[3];
    const float* Whh_f = (const float*)d_in[4];
    const float* b_f   = (const float*)d_in[5];
    const float* Wih_b = (const float*)d_in[6];
    const float* Whh_b = (const float*)d_in[7];
    const float* b_b   = (const float*)d_in[8];
    const float* W1    = (const float*)d_in[9];
    const float* b1    = (const float*)d_in[10];
    const float* W2    = (const float*)d_in[11];
    const float* b2    = (const float*)d_in[12];
    const float* Wu    = (const float*)d_in[13];
    const float* bu    = (const float*)d_in[14];
    const float* Wout  = (const float*)d_in[15];
    const float* bout  = (const float*)d_in[16];

    k1_lstm<<<8, 64, 0, stream>>>(sent, h0, c0, Wih_f, Whh_f, b_f,
                                  Wih_b, Whh_b, b_b);
    k2_proj<<<32, 256, 0, stream>>>(W1, b1, Wu, bu, Wout);
    k34_binary<<<1024, 256, 0, stream>>>(W2, b2, bout, (float*)d_out);
}

// Round 4
// 249.807 us; speedup vs baseline: 1.1896x; 1.1896x over previous
//
#include <hip/hip_runtime.h>
#include <hip/hip_bf16.h>
#include <math.h>

// Sizes (fixed by the problem)
#define BATCH 16
#define TLEN  512
#define HD    16     // per-direction hidden
#define HID   32     // 2*HD

typedef float v2f __attribute__((ext_vector_type(2)));

// Static device scratch — avoids any assumption about ws_size.
__device__ float g_outBT[BATCH * TLEN * HID];   // 1 MB
__device__ float g_preA [BATCH * TLEN * HID];   // 1 MB
__device__ float g_Ct   [BATCH * HID * TLEN];   // 1 MB
__device__ float g_un   [BATCH * TLEN];
__device__ float g_w2d  [BATCH * TLEN];
__device__ float g_accum[BATCH];                // zero-initialized, self-resetting
__device__ int   g_cnt  [BATCH];                // zero-initialized, self-resetting

__device__ __forceinline__ float sigm_(float x) {
    return 1.0f / (1.0f + __expf(-x));
}
__device__ __forceinline__ float tanh_(float x) {
    float e = __expf(2.0f * x);
    return 1.0f - 2.0f / (e + 1.0f);
}

// ---------------------------------------------------------------------------
// K1: bidirectional LSTM, round 10 — transposed parallelism (round-9 plan,
// compile fix: DPP control must be a LITERAL -> macro-expanded rotations).
// Rounds 6-8 post-mortem: with 64 (or even 32) weight floats per lane the
// compiler SINKS the weight loads into the t-loop (VGPR_Count 52/40 < working
// set, ~630 stall cyc/step re-fetching weights). Shrink the per-lane working
// set instead of fighting the allocator:
//   1 chain per wave (32 blocks = 16 b x 2 dir), lane r = gate row:
//   g = r>>4 (i,f,g,o), u = r&15 (unit). Dot = 16 terms -> 16 weights/lane.
// h is replicated per 16-lane row; 15 INDEPENDENT DPP row_ror:k deliver
// h[(u-k)&15]. Activation branch-free (per-lane constants em/mm/aa: exact
// sigm for i/f/o, exact tanh for g). Gate gather: 3 independent __shfl
// (lane^16/^32/^48) + cndmask ladder; every lane redundantly computes c,h
// for its unit -> h already broadcast for the next step.
// ---------------------------------------------------------------------------
__global__ __launch_bounds__(64, 1) void k1_lstm(
    const float* __restrict__ sent,   // [B,T]
    const float* __restrict__ h0,     // [2,B,16]
    const float* __restrict__ c0,     // [2,B,16]
    const float* __restrict__ Wih_f, const float* __restrict__ Whh_f, const float* __restrict__ b_f,
    const float* __restrict__ Wih_b, const float* __restrict__ Whh_b, const float* __restrict__ b_b)
{
    const int blk = blockIdx.x;       // 0..31
    const int dir = blk >> 4;         // 0 fwd, 1 bwd
    const int b   = blk & 15;         // batch
    const int r   = threadIdx.x;      // gate row 0..63
    const int u   = r & 15;           // unit
    const int g   = r >> 4;           // 0=i,1=f,2=g,3=o

    const float* Wih  = dir ? Wih_b : Wih_f;
    const float* Whh  = dir ? Whh_b : Whh_f;
    const float* bias = dir ? b_b   : b_f;

    // 16 recurrent weights for this gate row; wh[k] multiplies h[(u-k)&15].
    float wh[16];
    #pragma unroll
    for (int k = 0; k < 16; ++k) {
        const int m = (u - k) & 15;
        wh[k] = Whh[r * 16 + m];
        asm volatile("" : "+v"(wh[k]));   // pin in VGPR; forbid remat-into-loop
    }
    const float wx = Wih[r];
    const float bb = bias[r];

    // activation constants: i/f/o -> sigm(p), g -> tanh(p) (op-exact forms)
    const bool  isg = (g == 2);
    const float em  = isg ?  2.0f : -1.0f;   // exp argument multiplier
    const float mm  = isg ? -2.0f :  1.0f;   // post-scale
    const float aa  = isg ?  1.0f :  0.0f;   // post-offset

    const int p1 = r ^ 16, p2 = r ^ 32, p3 = r ^ 48;
    const bool gb0 = (g & 1) != 0;
    const bool gb1 = (g & 2) != 0;

    // replicated per-row state: h[u] and c[u]
    float hn = h0[dir * (BATCH * HD) + b * HD + u];
    float cc = c0[dir * (BATCH * HD) + b * HD + u];

    const float* srow = sent + b * TLEN;
    float* obase = g_outBT + (size_t)b * TLEN * HID + dir * HD + u;

    float4 xc = *(const float4*)(srow + (dir ? (TLEN - 4) : 0));
    for (int tb = 0; tb < TLEN; tb += 4) {
        float4 xn = xc;
        if (tb + 4 < TLEN)
            xn = *(const float4*)(srow + (dir ? (TLEN - 8 - tb) : (tb + 4)));
        float xa[4];
        if (dir) { xa[0] = xc.w; xa[1] = xc.z; xa[2] = xc.y; xa[3] = xc.x; }
        else     { xa[0] = xc.x; xa[1] = xc.y; xa[2] = xc.z; xa[3] = xc.w; }

        #pragma unroll
        for (int s2 = 0; s2 < 4; ++s2) {
            const int t   = tb + s2;
            const int pos = dir ? (TLEN - 1 - t) : t;
            const float x = xa[s2];

            // 15 independent rotations of this row's h copy (literal DPP ctl)
            const int r0i = __float_as_int(hn);
            float rot[16];
            rot[0] = hn;
#define ROT(K) rot[K] = __int_as_float( \
                __builtin_amdgcn_mov_dpp(r0i, 0x120 + K, 0xF, 0xF, true));
            ROT(1)  ROT(2)  ROT(3)  ROT(4)  ROT(5)  ROT(6)  ROT(7)
            ROT(8)  ROT(9)  ROT(10) ROT(11) ROT(12) ROT(13) ROT(14) ROT(15)
#undef ROT

            // 16-term dot, 4 accumulators (dep depth 4)
            float p  = fmaf(x, wx, bb);
            float a0 = fmaf(rot[0], wh[0], p);
            float a1 = rot[1] * wh[1];
            float a2 = rot[2] * wh[2];
            float a3 = rot[3] * wh[3];
            #pragma unroll
            for (int k = 4; k < 16; k += 4) {
                a0 = fmaf(rot[k + 0], wh[k + 0], a0);
                a1 = fmaf(rot[k + 1], wh[k + 1], a1);
                a2 = fmaf(rot[k + 2], wh[k + 2], a2);
                a3 = fmaf(rot[k + 3], wh[k + 3], a3);
            }
            p = (a0 + a1) + (a2 + a3);

            // branch-free activation
            const float e   = __expf(p * em);
            const float inv = 1.0f / (e + 1.0f);
            const float act = fmaf(mm, inv, aa);

            // gather the other three gate rows' activations (independent)
            const float x1 = __shfl(act, p1);
            const float x2 = __shfl(act, p2);
            const float x3 = __shfl(act, p3);

            // X[s] = act of row g^s; role j needs X[g^j]
            const float lo_i = gb0 ? x1  : act;
            const float hi_i = gb0 ? x3  : x2;
            const float ai   = gb1 ? hi_i : lo_i;     // X[g]
            const float lo_f = gb0 ? act : x1;
            const float hi_f = gb0 ? x2  : x3;
            const float af   = gb1 ? hi_f : lo_f;     // X[g^1]
            const float lo_g = gb0 ? x1  : act;
            const float hi_g = gb0 ? x3  : x2;
            const float ag   = gb1 ? lo_g : hi_g;     // X[g^2]
            const float lo_o = gb0 ? act : x1;
            const float hi_o = gb0 ? x2  : x3;
            const float ao   = gb1 ? lo_o : hi_o;     // X[g^3]

            cc = fmaf(af, cc, ai * ag);
            hn = ao * tanh_(cc);

            if (g == 0)
                obase[(size_t)pos * HID] = hn;
        }
        xc = xn;
    }
}

// ---------------------------------------------------------------------------
// K2: projections. Thread per (b,t). W1 etc. staged in LDS.
// ---------------------------------------------------------------------------
__global__ __launch_bounds__(256) void k2_proj(
    const float* __restrict__ W1,     // [32,64]
    const float* __restrict__ b1,     // [32]
    const float* __restrict__ Wu,     // [32]
    const float* __restrict__ bu,     // [1]
    const float* __restrict__ Wout)   // [32]
{
    __shared__ float w1s[HID * 64];
    __shared__ float b1s[HID], wus[HID], wos[HID];
    const int tid = threadIdx.x;
    for (int k = tid; k < HID * 64; k += 256) w1s[k] = W1[k];
    if (tid < HID) { b1s[tid] = b1[tid]; wus[tid] = Wu[tid]; wos[tid] = Wout[tid]; }
    __syncthreads();

    const int g = blockIdx.x * 256 + tid;    // 0..8191
    const int b = g >> 9;
    const int t = g & (TLEN - 1);

    float o[32];
    const float4* src = (const float4*)(g_outBT + (size_t)g * HID);
    #pragma unroll
    for (int qq = 0; qq < 8; ++qq) {
        float4 v = src[qq];
        o[qq * 4 + 0] = v.x; o[qq * 4 + 1] = v.y; o[qq * 4 + 2] = v.z; o[qq * 4 + 3] = v.w;
    }

    float* pa = g_preA + (size_t)g * HID;
    float* ct = g_Ct + (size_t)b * HID * TLEN + t;
    #pragma unroll 4
    for (int h = 0; h < HID; ++h) {
        float a = b1s[h], cacc = 0.f;
        const float* wr = &w1s[h * 64];
        #pragma unroll
        for (int k = 0; k < HID; ++k) {
            a    = fmaf(o[k], wr[k], a);
            cacc = fmaf(o[k], wr[32 + k], cacc);
        }
        pa[h] = a;
        ct[(size_t)h * TLEN] = cacc;
    }

    float ua = 0.f, wa = 0.f;
    #pragma unroll
    for (int k = 0; k < HID; ++k) { ua = fmaf(o[k], wus[k], ua); wa = fmaf(o[k], wos[k], wa); }
    g_un[g]  = ua + bu[0];
    g_w2d[g] = wa;
}

// ---------------------------------------------------------------------------
// K34: S[b,i] = sum_j sum_h relu(preA[b,i,h] + Ct[b,h,j]) * W2[h]
//      prob[b,i] = sigmoid((S - diag_i + 511*b2)/100 + un[b,i])
//      out[b] = sum_i prob[b,i]*w2d[b,i] / 512 + bout
// ---------------------------------------------------------------------------
__global__ __launch_bounds__(256) void k34_binary(
    const float* __restrict__ W2,     // [32]
    const float* __restrict__ b2p,    // [1]
    const float* __restrict__ boutp,  // [1]
    float* __restrict__ out)          // [16]
{
    const int b     = blockIdx.x >> 6;
    const int itile = blockIdx.x & 63;
    const int i0    = itile * 8;
    const int tid   = threadIdx.x;

    __shared__ float pa[8][HID];
    __shared__ float w2s[HID];
    __shared__ float redw[4][8];

    pa[tid >> 5][tid & 31] = g_preA[((size_t)b * TLEN + i0 + (tid >> 5)) * HID + (tid & 31)];
    if (tid < HID) w2s[tid] = W2[tid];
    __syncthreads();

    const float* ctb = g_Ct + (size_t)b * HID * TLEN;
    const int j0 = tid, j1 = tid + 256;

    float acc[8];
    #pragma unroll
    for (int ii = 0; ii < 8; ++ii) acc[ii] = 0.f;

    for (int h = 0; h < HID; ++h) {
        const float c0v = ctb[(size_t)h * TLEN + j0];
        const float c1v = ctb[(size_t)h * TLEN + j1];
        const float w   = w2s[h];
        #pragma unroll
        for (int ii = 0; ii < 8; ++ii) {
            const float p = pa[ii][h];
            acc[ii] = fmaf(fmaxf(p + c0v, 0.f), w, acc[ii]);
            acc[ii] = fmaf(fmaxf(p + c1v, 0.f), w, acc[ii]);
        }
    }

    #pragma unroll
    for (int ii = 0; ii < 8; ++ii) {
        float v = acc[ii];
        #pragma unroll
        for (int off = 32; off >= 1; off >>= 1) v += __shfl_down(v, off);
        if ((tid & 63) == 0) redw[tid >> 6][ii] = v;
    }
    __syncthreads();

    if (tid < 8) {
        const float S = redw[0][tid] + redw[1][tid] + redw[2][tid] + redw[3][tid];
        const int i = i0 + tid;
        float diag = 0.f;
        #pragma unroll
        for (int h = 0; h < HID; ++h)
            diag = fmaf(fmaxf(pa[tid][h] + ctb[(size_t)h * TLEN + i], 0.f), w2s[h], diag);
        const float b2 = b2p[0];
        const float s = (S - diag + (float)(TLEN - 1) * b2) * 0.01f + g_un[(size_t)b * TLEN + i];
        float contrib = sigm_(s) * g_w2d[(size_t)b * TLEN + i];
        contrib += __shfl_down(contrib, 4);
        contrib += __shfl_down(contrib, 2);
        contrib += __shfl_down(contrib, 1);
        if (tid == 0) {
            atomicAdd(&g_accum[b], contrib);
            __threadfence();
            int old = atomicAdd(&g_cnt[b], 1);
            if (old == 63) {
                __threadfence();
                float tot = atomicExch(&g_accum[b], 0.0f);
                out[b] = tot * (1.0f / (float)TLEN) + boutp[0];
                atomicExch(&g_cnt[b], 0);
            }
        }
    }
}

extern "C" void kernel_launch(void* const* d_in, const int* in_sizes, int n_in,
                              void* d_out, int out_size, void* d_ws, size_t ws_size,
                              hipStream_t stream) {
    const float* sent  = (const float*)d_in[0];
    const float* h0    = (const float*)d_in[1];
    const float* c0    = (const float*)d_in[2];
    const float* Wih_f = (const float*)d_in[3];
    const float* Whh_f = (const float*)d_in[4];
    const float* b_f   = (const float*)d_in[5];
    const float* Wih_b = (const float*)d_in[6];
    const float* Whh_b = (const float*)d_in[7];
    const float* b_b   = (const float*)d_in[8];
    const float* W1    = (const float*)d_in[9];
    const float* b1    = (const float*)d_in[10];
    const float* W2    = (const float*)d_in[11];
    const float* b2    = (const float*)d_in[12];
    const float* Wu    = (const float*)d_in[13];
    const float* bu    = (const float*)d_in[14];
    const float* Wout  = (const float*)d_in[15];
    const float* bout  = (const float*)d_in[16];

    k1_lstm<<<32, 64, 0, stream>>>(sent, h0, c0, Wih_f, Whh_f, b_f,
                                   Wih_b, Whh_b, b_b);
    k2_proj<<<32, 256, 0, stream>>>(W1, b1, Wu, bu, Wout);
    k34_binary<<<1024, 256, 0, stream>>>(W2, b2, bout, (float*)d_out);
}

// Round 5
// 242.922 us; speedup vs baseline: 1.2233x; 1.0283x over previous
//
#include <hip/hip_runtime.h>
#include <hip/hip_bf16.h>
#include <math.h>

// Sizes (fixed by the problem)
#define BATCH 16
#define TLEN  512
#define HD    16     // per-direction hidden
#define HID   32     // 2*HD

typedef float v2f __attribute__((ext_vector_type(2)));
typedef unsigned u2v __attribute__((ext_vector_type(2)));

// Static device scratch — avoids any assumption about ws_size.
__device__ float g_outBT[BATCH * TLEN * HID];   // 1 MB
__device__ float g_preA [BATCH * TLEN * HID];   // 1 MB
__device__ float g_Ct   [BATCH * HID * TLEN];   // 1 MB
__device__ float g_un   [BATCH * TLEN];
__device__ float g_w2d  [BATCH * TLEN];
__device__ float g_accum[BATCH];                // zero-initialized, self-resetting
__device__ int   g_cnt  [BATCH];                // zero-initialized, self-resetting

__device__ __forceinline__ float sigm_(float x) {
    return 1.0f / (1.0f + __expf(-x));
}
__device__ __forceinline__ float tanh_(float x) {
    float e = __expf(2.0f * x);
    return 1.0f - 2.0f / (e + 1.0f);
}

// ---------------------------------------------------------------------------
// K1: bidirectional LSTM, round 11.
// Round-10 landed the transposed structure (1 chain/wave, lane = gate row):
// 162 -> 118 us. Per-step is now ~552 cyc with ~75 cyc of VALU issue: pure
// serial LATENCY, one wave per SIMD. Biggest removable term: the 3x __shfl
// gate-gather = ds_bpermute on the LDS pipe (~120 cyc single-outstanding,
// m117) + s_waitcnt lgkmcnt(0).
// This round: replace the gather with gfx950 v_permlane16/32_swap_b32
// (VALU cross-lane, ~4-8 cyc, no lgkm wait). With swap(act,act):
//   permlane16: d' rows=[r0,r0,r2,r2], s' rows=[r1,r1,r3,r3] -> x1 = g&1?d':s'
//   permlane32: d' rows=[r0,r1,r0,r1], s' rows=[r2,r3,r2,r3] -> x2 = g&2?d':s'
//   permlane16 of x2 (rows [r2,r3,r0,r1]): d3=[r2,r2,r0,r0], s3=[r3,r3,r1,r1]
//     -> x3 = g&1?d3:s3
// (verified lane-by-lane: x1/x2/x3 == act from lane r^16 / r^32 / r^48).
// Guarded by __has_builtin; falls back to __shfl (round-10 behavior).
// Stores batched: 4 hn values kept in registers, one if(g==0) block per chunk.
// ---------------------------------------------------------------------------
__global__ __launch_bounds__(64, 1) void k1_lstm(
    const float* __restrict__ sent,   // [B,T]
    const float* __restrict__ h0,     // [2,B,16]
    const float* __restrict__ c0,     // [2,B,16]
    const float* __restrict__ Wih_f, const float* __restrict__ Whh_f, const float* __restrict__ b_f,
    const float* __restrict__ Wih_b, const float* __restrict__ Whh_b, const float* __restrict__ b_b)
{
    const int blk = blockIdx.x;       // 0..31
    const int dir = blk >> 4;         // 0 fwd, 1 bwd
    const int b   = blk & 15;         // batch
    const int r   = threadIdx.x;      // gate row 0..63
    const int u   = r & 15;           // unit
    const int g   = r >> 4;           // 0=i,1=f,2=g,3=o

    const float* Wih  = dir ? Wih_b : Wih_f;
    const float* Whh  = dir ? Whh_b : Whh_f;
    const float* bias = dir ? b_b   : b_f;

    // 16 recurrent weights for this gate row; wh[k] multiplies h[(u-k)&15].
    float wh[16];
    #pragma unroll
    for (int k = 0; k < 16; ++k) {
        const int m = (u - k) & 15;
        wh[k] = Whh[r * 16 + m];
        asm volatile("" : "+v"(wh[k]));   // pin; forbid remat-into-loop
    }
    const float wx = Wih[r];
    const float bb = bias[r];

    // activation constants: i/f/o -> sigm(p), g -> tanh(p) (op-exact forms)
    const bool  isg = (g == 2);
    const float em  = isg ?  2.0f : -1.0f;   // exp argument multiplier
    const float mm  = isg ? -2.0f :  1.0f;   // post-scale
    const float aa  = isg ?  1.0f :  0.0f;   // post-offset

    const bool gb0 = (g & 1) != 0;
    const bool gb1 = (g & 2) != 0;
#if !__has_builtin(__builtin_amdgcn_permlane16_swap) || !__has_builtin(__builtin_amdgcn_permlane32_swap)
    const int p1 = r ^ 16, p2 = r ^ 32, p3 = r ^ 48;
#endif

    // replicated per-row state: h[u] and c[u]
    float hn = h0[dir * (BATCH * HD) + b * HD + u];
    float cc = c0[dir * (BATCH * HD) + b * HD + u];

    const float* srow = sent + b * TLEN;
    float* obase = g_outBT + (size_t)b * TLEN * HID + dir * HD + u;

    float4 xc = *(const float4*)(srow + (dir ? (TLEN - 4) : 0));
    for (int tb = 0; tb < TLEN; tb += 4) {
        float4 xn = xc;
        if (tb + 4 < TLEN)
            xn = *(const float4*)(srow + (dir ? (TLEN - 8 - tb) : (tb + 4)));
        float xa[4];
        if (dir) { xa[0] = xc.w; xa[1] = xc.z; xa[2] = xc.y; xa[3] = xc.x; }
        else     { xa[0] = xc.x; xa[1] = xc.y; xa[2] = xc.z; xa[3] = xc.w; }

        float hsave[4];

        #pragma unroll
        for (int s2 = 0; s2 < 4; ++s2) {
            const float x = xa[s2];

            // 15 independent rotations of this row's h copy (literal DPP ctl)
            const int r0i = __float_as_int(hn);
            float rot[16];
            rot[0] = hn;
#define ROT(K) rot[K] = __int_as_float( \
                __builtin_amdgcn_mov_dpp(r0i, 0x120 + K, 0xF, 0xF, true));
            ROT(1)  ROT(2)  ROT(3)  ROT(4)  ROT(5)  ROT(6)  ROT(7)
            ROT(8)  ROT(9)  ROT(10) ROT(11) ROT(12) ROT(13) ROT(14) ROT(15)
#undef ROT

            // 16-term dot, 4 accumulators (dep depth 4)
            float p  = fmaf(x, wx, bb);
            float a0 = fmaf(rot[0], wh[0], p);
            float a1 = rot[1] * wh[1];
            float a2 = rot[2] * wh[2];
            float a3 = rot[3] * wh[3];
            #pragma unroll
            for (int k = 4; k < 16; k += 4) {
                a0 = fmaf(rot[k + 0], wh[k + 0], a0);
                a1 = fmaf(rot[k + 1], wh[k + 1], a1);
                a2 = fmaf(rot[k + 2], wh[k + 2], a2);
                a3 = fmaf(rot[k + 3], wh[k + 3], a3);
            }
            p = (a0 + a1) + (a2 + a3);

            // branch-free activation
            const float e   = __expf(p * em);
            const float inv = 1.0f / (e + 1.0f);
            const float act = fmaf(mm, inv, aa);

            // gather the other three gate rows' activations
            float x1, x2, x3;
#if __has_builtin(__builtin_amdgcn_permlane16_swap) && __has_builtin(__builtin_amdgcn_permlane32_swap)
            {
                const unsigned ai_ = (unsigned)__float_as_int(act);
                u2v q16 = __builtin_amdgcn_permlane16_swap(ai_, ai_, false, false);
                x1 = __int_as_float((int)(gb0 ? q16[0] : q16[1]));
                u2v q32 = __builtin_amdgcn_permlane32_swap(ai_, ai_, false, false);
                const unsigned x2i = gb1 ? q32[0] : q32[1];
                x2 = __int_as_float((int)x2i);
                u2v q48 = __builtin_amdgcn_permlane16_swap(x2i, x2i, false, false);
                x3 = __int_as_float((int)(gb0 ? q48[0] : q48[1]));
            }
#else
            x1 = __shfl(act, p1);
            x2 = __shfl(act, p2);
            x3 = __shfl(act, p3);
#endif

            // X[s] = act of row g^s; role j needs X[g^j]
            const float lo_i = gb0 ? x1  : act;
            const float hi_i = gb0 ? x3  : x2;
            const float ai   = gb1 ? hi_i : lo_i;     // X[g]
            const float lo_f = gb0 ? act : x1;
            const float hi_f = gb0 ? x2  : x3;
            const float af   = gb1 ? hi_f : lo_f;     // X[g^1]
            const float lo_g = gb0 ? x1  : act;
            const float hi_g = gb0 ? x3  : x2;
            const float ag   = gb1 ? lo_g : hi_g;     // X[g^2]
            const float lo_o = gb0 ? act : x1;
            const float hi_o = gb0 ? x2  : x3;
            const float ao   = gb1 ? lo_o : hi_o;     // X[g^3]

            cc = fmaf(af, cc, ai * ag);
            hn = ao * tanh_(cc);
            hsave[s2] = hn;
        }

        // batched store: one exec-mask toggle per 4 steps
        if (g == 0) {
            if (dir) {
                const int pos0 = TLEN - 1 - tb;      // pos = pos0 - s2
                obase[(size_t)(pos0    ) * HID] = hsave[0];
                obase[(size_t)(pos0 - 1) * HID] = hsave[1];
                obase[(size_t)(pos0 - 2) * HID] = hsave[2];
                obase[(size_t)(pos0 - 3) * HID] = hsave[3];
            } else {
                obase[(size_t)(tb    ) * HID] = hsave[0];
                obase[(size_t)(tb + 1) * HID] = hsave[1];
                obase[(size_t)(tb + 2) * HID] = hsave[2];
                obase[(size_t)(tb + 3) * HID] = hsave[3];
            }
        }
        xc = xn;
    }
}

// ---------------------------------------------------------------------------
// K2: projections. Thread per (b,t). W1 etc. staged in LDS.
// ---------------------------------------------------------------------------
__global__ __launch_bounds__(256) void k2_proj(
    const float* __restrict__ W1,     // [32,64]
    const float* __restrict__ b1,     // [32]
    const float* __restrict__ Wu,     // [32]
    const float* __restrict__ bu,     // [1]
    const float* __restrict__ Wout)   // [32]
{
    __shared__ float w1s[HID * 64];
    __shared__ float b1s[HID], wus[HID], wos[HID];
    const int tid = threadIdx.x;
    for (int k = tid; k < HID * 64; k += 256) w1s[k] = W1[k];
    if (tid < HID) { b1s[tid] = b1[tid]; wus[tid] = Wu[tid]; wos[tid] = Wout[tid]; }
    __syncthreads();

    const int g = blockIdx.x * 256 + tid;    // 0..8191
    const int b = g >> 9;
    const int t = g & (TLEN - 1);

    float o[32];
    const float4* src = (const float4*)(g_outBT + (size_t)g * HID);
    #pragma unroll
    for (int qq = 0; qq < 8; ++qq) {
        float4 v = src[qq];
        o[qq * 4 + 0] = v.x; o[qq * 4 + 1] = v.y; o[qq * 4 + 2] = v.z; o[qq * 4 + 3] = v.w;
    }

    float* pa = g_preA + (size_t)g * HID;
    float* ct = g_Ct + (size_t)b * HID * TLEN + t;
    #pragma unroll 4
    for (int h = 0; h < HID; ++h) {
        float a = b1s[h], cacc = 0.f;
        const float* wr = &w1s[h * 64];
        #pragma unroll
        for (int k = 0; k < HID; ++k) {
            a    = fmaf(o[k], wr[k], a);
            cacc = fmaf(o[k], wr[32 + k], cacc);
        }
        pa[h] = a;
        ct[(size_t)h * TLEN] = cacc;
    }

    float ua = 0.f, wa = 0.f;
    #pragma unroll
    for (int k = 0; k < HID; ++k) { ua = fmaf(o[k], wus[k], ua); wa = fmaf(o[k], wos[k], wa); }
    g_un[g]  = ua + bu[0];
    g_w2d[g] = wa;
}

// ---------------------------------------------------------------------------
// K34: S[b,i] = sum_j sum_h relu(preA[b,i,h] + Ct[b,h,j]) * W2[h]
//      prob[b,i] = sigmoid((S - diag_i + 511*b2)/100 + un[b,i])
//      out[b] = sum_i prob[b,i]*w2d[b,i] / 512 + bout
// Round 11: h-loops fully unrolled so the Ct loads batch (many in flight)
// instead of issuing 2 per iteration with interleaved waits.
// ---------------------------------------------------------------------------
__global__ __launch_bounds__(256) void k34_binary(
    const float* __restrict__ W2,     // [32]
    const float* __restrict__ b2p,    // [1]
    const float* __restrict__ boutp,  // [1]
    float* __restrict__ out)          // [16]
{
    const int b     = blockIdx.x >> 6;
    const int itile = blockIdx.x & 63;
    const int i0    = itile * 8;
    const int tid   = threadIdx.x;

    __shared__ float pa[8][HID];
    __shared__ float w2s[HID];
    __shared__ float redw[4][8];

    pa[tid >> 5][tid & 31] = g_preA[((size_t)b * TLEN + i0 + (tid >> 5)) * HID + (tid & 31)];
    if (tid < HID) w2s[tid] = W2[tid];
    __syncthreads();

    const float* ctb = g_Ct + (size_t)b * HID * TLEN;
    const int j0 = tid, j1 = tid + 256;

    float acc[8];
    #pragma unroll
    for (int ii = 0; ii < 8; ++ii) acc[ii] = 0.f;

    #pragma unroll 8
    for (int h = 0; h < HID; ++h) {
        const float c0v = ctb[(size_t)h * TLEN + j0];
        const float c1v = ctb[(size_t)h * TLEN + j1];
        const float w   = w2s[h];
        #pragma unroll
        for (int ii = 0; ii < 8; ++ii) {
            const float p = pa[ii][h];
            acc[ii] = fmaf(fmaxf(p + c0v, 0.f), w, acc[ii]);
            acc[ii] = fmaf(fmaxf(p + c1v, 0.f), w, acc[ii]);
        }
    }

    #pragma unroll
    for (int ii = 0; ii < 8; ++ii) {
        float v = acc[ii];
        #pragma unroll
        for (int off = 32; off >= 1; off >>= 1) v += __shfl_down(v, off);
        if ((tid & 63) == 0) redw[tid >> 6][ii] = v;
    }
    __syncthreads();

    if (tid < 8) {
        const float S = redw[0][tid] + redw[1][tid] + redw[2][tid] + redw[3][tid];
        const int i = i0 + tid;
        float diag = 0.f;
        #pragma unroll
        for (int h = 0; h < HID; ++h)
            diag = fmaf(fmaxf(pa[tid][h] + ctb[(size_t)h * TLEN + i], 0.f), w2s[h], diag);
        const float b2 = b2p[0];
        const float s = (S - diag + (float)(TLEN - 1) * b2) * 0.01f + g_un[(size_t)b * TLEN + i];
        float contrib = sigm_(s) * g_w2d[(size_t)b * TLEN + i];
        contrib += __shfl_down(contrib, 4);
        contrib += __shfl_down(contrib, 2);
        contrib += __shfl_down(contrib, 1);
        if (tid == 0) {
            atomicAdd(&g_accum[b], contrib);
            __threadfence();
            int old = atomicAdd(&g_cnt[b], 1);
            if (old == 63) {
                __threadfence();
                float tot = atomicExch(&g_accum[b], 0.0f);
                out[b] = tot * (1.0f / (float)TLEN) + boutp[0];
                atomicExch(&g_cnt[b], 0);
            }
        }
    }
}

extern "C" void kernel_launch(void* const* d_in, const int* in_sizes, int n_in,
                              void* d_out, int out_size, void* d_ws, size_t ws_size,
                              hipStream_t stream) {
    const float* sent  = (const float*)d_in[0];
    const float* h0    = (const float*)d_in[1];
    const float* c0    = (const float*)d_in[2];
    const float* Wih_f = (const float*)d_in[3];
    const float* Whh_f = (const float*)d_in[4];
    const float* b_f   = (const float*)d_in[5];
    const float* Wih_b = (const float*)d_in[6];
    const float* Whh_b = (const float*)d_in[7];
    const float* b_b   = (const float*)d_in[8];
    const float* W1    = (const float*)d_in[9];
    const float* b1    = (const float*)d_in[10];
    const float* W2    = (const float*)d_in[11];
    const float* b2    = (const float*)d_in[12];
    const float* Wu    = (const float*)d_in[13];
    const float* bu    = (const float*)d_in[14];
    const float* Wout  = (const float*)d_in[15];
    const float* bout  = (const float*)d_in[16];

    k1_lstm<<<32, 64, 0, stream>>>(sent, h0, c0, Wih_f, Whh_f, b_f,
                                   Wih_b, Whh_b, b_b);
    k2_proj<<<32, 256, 0, stream>>>(W1, b1, Wu, bu, Wout);
    k34_binary<<<1024, 256, 0, stream>>>(W2, b2, bout, (float*)d_out);
}

// Round 6
// 236.437 us; speedup vs baseline: 1.2569x; 1.0274x over previous
//
#include <hip/hip_runtime.h>
#include <hip/hip_bf16.h>
#include <math.h>

// Sizes (fixed by the problem)
#define BATCH 16
#define TLEN  512
#define HD    16     // per-direction hidden
#define HID   32     // 2*HD

typedef float v2f __attribute__((ext_vector_type(2)));
typedef unsigned u2v __attribute__((ext_vector_type(2)));

// Static device scratch — avoids any assumption about ws_size.
__device__ float g_outBT[BATCH * TLEN * HID];   // 1 MB
__device__ float g_preA [BATCH * TLEN * HID];   // 1 MB
__device__ float g_Ct   [BATCH * HID * TLEN];   // 1 MB
__device__ float g_un   [BATCH * TLEN];
__device__ float g_w2d  [BATCH * TLEN];
__device__ float g_accum[BATCH];                // zero-initialized, self-resetting
__device__ int   g_cnt  [BATCH];                // zero-initialized, self-resetting

__device__ __forceinline__ float sigm_(float x) {
    return 1.0f / (1.0f + __expf(-x));
}

__device__ __forceinline__ float ex2_(float x) {
#if __has_builtin(__builtin_amdgcn_exp2f)
    return __builtin_amdgcn_exp2f(x);     // raw v_exp_f32 (2^x)
#else
    return exp2f(x);
#endif
}
__device__ __forceinline__ float rcp_(float x) {
#if __has_builtin(__builtin_amdgcn_rcpf)
    return __builtin_amdgcn_rcpf(x);      // raw v_rcp_f32 — avoids IEEE div chain
#else
    return 1.0f / x;
#endif
}

__device__ __forceinline__ v2f pk_fma(v2f a, v2f b, v2f c) {
#if __has_builtin(__builtin_elementwise_fma)
    return __builtin_elementwise_fma(a, b, c);   // -> v_pk_fma_f32
#else
    v2f r; r.x = fmaf(a.x, b.x, c.x); r.y = fmaf(a.y, b.y, c.y); return r;
#endif
}

// ---------------------------------------------------------------------------
// K1: bidirectional LSTM, round 12 — latency surgery on the serial step.
// Round-11 post-mortem: step ~512 cyc, only ~88 cyc VALU issue. Two mis-modeled
// latency sinks: (1) 1.0f/x compiles to the IEEE div sequence (~55 cyc x2 per
// step) -> use raw v_rcp_f32; (2) dependent-VALU latency ~6-8 cyc across a
// ~45-op chain -> cut chain depth:
//   - fold exp-arg scales into weights/bias at init (sigm: -log2e; tanh-gate:
//     +2*log2e) so the dot feeds v_exp_f32 (=2^x) directly; keep the c state
//     scaled by 2*log2e so tanh(c) also needs no pre-mul (gate-g activation
//     emits 2log2e*tanh via adjusted mm/aa constants).
//   - 2 chains per wave (fwd+bwd of one batch): lane = (dir=lane>>5,
//     ps=(lane>>4)&1 selecting gate pair (i,f)/(g,o), u=lane&15). Gates
//     computed 2-wide via v_pk_fma_f32 (16 weights -> 16 v2f = 32 floats/lane,
//     pinned). Gate gather = ONE permlane16_swap per component + 4 cndmasks
//     (partner row holds the other gate pair positionally — no select ladder);
//     c,h fully in-lane, replicated per row so DPP row_ror:k works as before.
// Mapping from round-5-verified swap semantics: value-from-lane^16 =
// ps ? q[0] : q[1] (row0<->row1, row2<->row3 — chain-internal).
// ---------------------------------------------------------------------------
__global__ __launch_bounds__(64, 1) void k1_lstm(
    const float* __restrict__ sent,   // [B,T]
    const float* __restrict__ h0,     // [2,B,16]
    const float* __restrict__ c0,     // [2,B,16]
    const float* __restrict__ Wih_f, const float* __restrict__ Whh_f, const float* __restrict__ b_f,
    const float* __restrict__ Wih_b, const float* __restrict__ Whh_b, const float* __restrict__ b_b)
{
    const int b    = blockIdx.x;       // 0..15
    const int lane = threadIdx.x;
    const int dir  = lane >> 5;        // 0 fwd (lanes 0-31), 1 bwd (32-63)
    const int ps   = (lane >> 4) & 1;  // 0 -> gates (i,f), 1 -> gates (g,o)
    const int u    = lane & 15;        // unit

    const float* Wih  = dir ? Wih_b : Wih_f;
    const float* Whh  = dir ? Whh_b : Whh_f;
    const float* bias = dir ? b_b   : b_f;

    const float L2E = 1.4426950408889634f;
    // exp-argument scales folded into weights: sigm uses 2^(-log2e*p),
    // tanh-gate uses 2^(2*log2e*p).
    const float sA = ps ? (2.0f * L2E) : (-L2E);  // gate g : gate i
    const float sB = -L2E;                        // gates f and o (sigm)
    const int gA = ps ? 2 : 0, gB = ps ? 3 : 1;   // torch order i,f,g,o
    const int rA = u + 16 * gA, rB = u + 16 * gB;

    // 16 packed recurrent weights; wv[k] multiplies h[(u-k)&15].
    v2f wv[16];
    #pragma unroll
    for (int k = 0; k < 16; ++k) {
        const int m = (u - k) & 15;
        wv[k].x = Whh[rA * 16 + m] * sA;
        wv[k].y = Whh[rB * 16 + m] * sB;
        asm volatile("" : "+v"(wv[k]));   // pin pair; forbid remat-into-loop
    }
    v2f wx2; wx2.x = Wih[rA] * sA;  wx2.y = Wih[rB] * sB;
    v2f bb2; bb2.x = bias[rA] * sA; bb2.y = bias[rB] * sB;
    // activation: act = fma(mm, rcp(2^p' + 1), aa)
    //  sigm gates: mm=1, aa=0.  gate g (emits 2log2e*tanh): mm=-4log2e, aa=2log2e
    v2f mm2; mm2.x = ps ? (-4.0f * L2E) : 1.0f; mm2.y = 1.0f;
    v2f aa2; aa2.x = ps ? ( 2.0f * L2E) : 0.0f; aa2.y = 0.0f;

    // replicated per-row state; c tracked scaled by 2*log2e
    float hn = h0[dir * (BATCH * HD) + b * HD + u];
    float cc = c0[dir * (BATCH * HD) + b * HD + u] * (2.0f * L2E);

    const float* srow = sent + b * TLEN;
    float* obase = g_outBT + (size_t)b * TLEN * HID + dir * HD + u;
    const int sg = dir ? -HID : HID;    // per-step store stride (elements)

    float4 xc = *(const float4*)(srow + (dir ? (TLEN - 4) : 0));
    for (int tb = 0; tb < TLEN; tb += 4) {
        float4 xn = xc;
        if (tb + 4 < TLEN)
            xn = *(const float4*)(srow + (dir ? (TLEN - 8 - tb) : (tb + 4)));
        const float fx0 = xc.x, fx1 = xc.y, fx2 = xc.z, fx3 = xc.w;

        float hsave[4];

        #pragma unroll
        for (int s2 = 0; s2 < 4; ++s2) {
            // per-step x: fwd consumes s2, bwd consumes 3-s2 (reversed chunk)
            const float x = dir ? (s2 == 0 ? fx3 : s2 == 1 ? fx2 : s2 == 2 ? fx1 : fx0)
                                : (s2 == 0 ? fx0 : s2 == 1 ? fx1 : s2 == 2 ? fx2 : fx3);

            // 15 independent rotations of this row's h copy (literal DPP ctl)
            const int r0i = __float_as_int(hn);
            float rot[16];
            rot[0] = hn;
#define ROT(K) rot[K] = __int_as_float( \
                __builtin_amdgcn_mov_dpp(r0i, 0x120 + K, 0xF, 0xF, true));
            ROT(1)  ROT(2)  ROT(3)  ROT(4)  ROT(5)  ROT(6)  ROT(7)
            ROT(8)  ROT(9)  ROT(10) ROT(11) ROT(12) ROT(13) ROT(14) ROT(15)
#undef ROT

            // packed 16-term dot for both gates, 4 v2f accumulators
            v2f xv; xv.x = x; xv.y = x;
            v2f a0 = pk_fma(xv, wx2, bb2);
            v2f hv0; hv0.x = rot[0]; hv0.y = rot[0];
            a0 = pk_fma(wv[0], hv0, a0);
            v2f hv1; hv1.x = rot[1]; hv1.y = rot[1];
            v2f a1 = wv[1] * hv1;
            v2f hv2; hv2.x = rot[2]; hv2.y = rot[2];
            v2f a2 = wv[2] * hv2;
            v2f hv3; hv3.x = rot[3]; hv3.y = rot[3];
            v2f a3 = wv[3] * hv3;
            #pragma unroll
            for (int k = 4; k < 16; k += 4) {
                v2f h0v; h0v.x = rot[k + 0]; h0v.y = rot[k + 0];
                v2f h1v; h1v.x = rot[k + 1]; h1v.y = rot[k + 1];
                v2f h2v; h2v.x = rot[k + 2]; h2v.y = rot[k + 2];
                v2f h3v; h3v.x = rot[k + 3]; h3v.y = rot[k + 3];
                a0 = pk_fma(wv[k + 0], h0v, a0);
                a1 = pk_fma(wv[k + 1], h1v, a1);
                a2 = pk_fma(wv[k + 2], h2v, a2);
                a3 = pk_fma(wv[k + 3], h3v, a3);
            }
            v2f p2 = (a0 + a1) + (a2 + a3);   // pre-acts, exp-scale folded in

            // activation: e = 2^p', inv = rcp(e+1), act = fma(mm, inv, aa)
            v2f ee;  ee.x  = ex2_(p2.x);        ee.y  = ex2_(p2.y);
            v2f iv;  iv.x  = rcp_(ee.x + 1.0f); iv.y  = rcp_(ee.y + 1.0f);
            v2f act = pk_fma(mm2, iv, aa2);
            // ps0 lanes: act = (ai, af).  ps1 lanes: act = (2log2e*tanh_g, ao)

            // partner gate pair via one swap per component (lane^16)
            float swx, swy;
            {
                const unsigned axi = (unsigned)__float_as_int(act.x);
                u2v qx = __builtin_amdgcn_permlane16_swap(axi, axi, false, false);
                swx = __int_as_float((int)(ps ? qx[0] : qx[1]));
                const unsigned ayi = (unsigned)__float_as_int(act.y);
                u2v qy = __builtin_amdgcn_permlane16_swap(ayi, ayi, false, false);
                swy = __int_as_float((int)(ps ? qy[0] : qy[1]));
            }
            const float ai = ps ? swx  : act.x;
            const float af = ps ? swy  : act.y;
            const float ag = ps ? act.x : swx;   // = 2log2e * tanh(p_g)
            const float ao = ps ? act.y : swy;

            // c' = af*c' + ai*(2log2e*tanh_g)   (c' = 2log2e * c)
            cc = fmaf(af, cc, ai * ag);
            // tanh(c) = 1 - 2/(2^c' + 1)
            const float e2   = ex2_(cc);
            const float inv2 = rcp_(e2 + 1.0f);
            const float z    = fmaf(-2.0f, inv2, 1.0f);
            hn = ao * z;
            hsave[s2] = hn;
        }

        // batched store: ps==0 rows (lanes 0-15 fwd, 32-47 bwd)
        if (ps == 0) {
            float* bp = obase + (size_t)(dir ? (TLEN - 1 - tb) : tb) * HID;
            bp[0]      = hsave[0];
            bp[sg]     = hsave[1];
            bp[2 * sg] = hsave[2];
            bp[3 * sg] = hsave[3];
        }
        xc = xn;
    }
}

// ---------------------------------------------------------------------------
// K2: projections. Thread per (b,t). W1 etc. staged in LDS.
// ---------------------------------------------------------------------------
__global__ __launch_bounds__(256) void k2_proj(
    const float* __restrict__ W1,     // [32,64]
    const float* __restrict__ b1,     // [32]
    const float* __restrict__ Wu,     // [32]
    const float* __restrict__ bu,     // [1]
    const float* __restrict__ Wout)   // [32]
{
    __shared__ float w1s[HID * 64];
    __shared__ float b1s[HID], wus[HID], wos[HID];
    const int tid = threadIdx.x;
    for (int k = tid; k < HID * 64; k += 256) w1s[k] = W1[k];
    if (tid < HID) { b1s[tid] = b1[tid]; wus[tid] = Wu[tid]; wos[tid] = Wout[tid]; }
    __syncthreads();

    const int g = blockIdx.x * 256 + tid;    // 0..8191
    const int b = g >> 9;
    const int t = g & (TLEN - 1);

    float o[32];
    const float4* src = (const float4*)(g_outBT + (size_t)g * HID);
    #pragma unroll
    for (int qq = 0; qq < 8; ++qq) {
        float4 v = src[qq];
        o[qq * 4 + 0] = v.x; o[qq * 4 + 1] = v.y; o[qq * 4 + 2] = v.z; o[qq * 4 + 3] = v.w;
    }

    float* pa = g_preA + (size_t)g * HID;
    float* ct = g_Ct + (size_t)b * HID * TLEN + t;
    #pragma unroll 4
    for (int h = 0; h < HID; ++h) {
        float a = b1s[h], cacc = 0.f;
        const float* wr = &w1s[h * 64];
        #pragma unroll
        for (int k = 0; k < HID; ++k) {
            a    = fmaf(o[k], wr[k], a);
            cacc = fmaf(o[k], wr[32 + k], cacc);
        }
        pa[h] = a;
        ct[(size_t)h * TLEN] = cacc;
    }

    float ua = 0.f, wa = 0.f;
    #pragma unroll
    for (int k = 0; k < HID; ++k) { ua = fmaf(o[k], wus[k], ua); wa = fmaf(o[k], wos[k], wa); }
    g_un[g]  = ua + bu[0];
    g_w2d[g] = wa;
}

// ---------------------------------------------------------------------------
// K34: S[b,i] = sum_j sum_h relu(preA[b,i,h] + Ct[b,h,j]) * W2[h]
//      prob[b,i] = sigmoid((S - diag_i + 511*b2)/100 + un[b,i])
//      out[b] = sum_i prob[b,i]*w2d[b,i] / 512 + bout
// ---------------------------------------------------------------------------
__global__ __launch_bounds__(256) void k34_binary(
    const float* __restrict__ W2,     // [32]
    const float* __restrict__ b2p,    // [1]
    const float* __restrict__ boutp,  // [1]
    float* __restrict__ out)          // [16]
{
    const int b     = blockIdx.x >> 6;
    const int itile = blockIdx.x & 63;
    const int i0    = itile * 8;
    const int tid   = threadIdx.x;

    __shared__ float pa[8][HID];
    __shared__ float w2s[HID];
    __shared__ float redw[4][8];

    pa[tid >> 5][tid & 31] = g_preA[((size_t)b * TLEN + i0 + (tid >> 5)) * HID + (tid & 31)];
    if (tid < HID) w2s[tid] = W2[tid];
    __syncthreads();

    const float* ctb = g_Ct + (size_t)b * HID * TLEN;
    const int j0 = tid, j1 = tid + 256;

    float acc[8];
    #pragma unroll
    for (int ii = 0; ii < 8; ++ii) acc[ii] = 0.f;

    #pragma unroll 8
    for (int h = 0; h < HID; ++h) {
        const float c0v = ctb[(size_t)h * TLEN + j0];
        const float c1v = ctb[(size_t)h * TLEN + j1];
        const float w   = w2s[h];
        #pragma unroll
        for (int ii = 0; ii < 8; ++ii) {
            const float p = pa[ii][h];
            acc[ii] = fmaf(fmaxf(p + c0v, 0.f), w, acc[ii]);
            acc[ii] = fmaf(fmaxf(p + c1v, 0.f), w, acc[ii]);
        }
    }

    #pragma unroll
    for (int ii = 0; ii < 8; ++ii) {
        float v = acc[ii];
        #pragma unroll
        for (int off = 32; off >= 1; off >>= 1) v += __shfl_down(v, off);
        if ((tid & 63) == 0) redw[tid >> 6][ii] = v;
    }
    __syncthreads();

    if (tid < 8) {
        const float S = redw[0][tid] + redw[1][tid] + redw[2][tid] + redw[3][tid];
        const int i = i0 + tid;
        float diag = 0.f;
        #pragma unroll
        for (int h = 0; h < HID; ++h)
            diag = fmaf(fmaxf(pa[tid][h] + ctb[(size_t)h * TLEN + i], 0.f), w2s[h], diag);
        const float b2 = b2p[0];
        const float s = (S - diag + (float)(TLEN - 1) * b2) * 0.01f + g_un[(size_t)b * TLEN + i];
        float contrib = sigm_(s) * g_w2d[(size_t)b * TLEN + i];
        contrib += __shfl_down(contrib, 4);
        contrib += __shfl_down(contrib, 2);
        contrib += __shfl_down(contrib, 1);
        if (tid == 0) {
            atomicAdd(&g_accum[b], contrib);
            __threadfence();
            int old = atomicAdd(&g_cnt[b], 1);
            if (old == 63) {
                __threadfence();
                float tot = atomicExch(&g_accum[b], 0.0f);
                out[b] = tot * (1.0f / (float)TLEN) + boutp[0];
                atomicExch(&g_cnt[b], 0);
            }
        }
    }
}

extern "C" void kernel_launch(void* const* d_in, const int* in_sizes, int n_in,
                              void* d_out, int out_size, void* d_ws, size_t ws_size,
                              hipStream_t stream) {
    const float* sent  = (const float*)d_in[0];
    const float* h0    = (const float*)d_in[1];
    const float* c0    = (const float*)d_in[2];
    const float* Wih_f = (const float*)d_in[3];
    const float* Whh_f = (const float*)d_in[4];
    const float* b_f   = (const float*)d_in[5];
    const float* Wih_b = (const float*)d_in[6];
    const float* Whh_b = (const float*)d_in[7];
    const float* b_b   = (const float*)d_in[8];
    const float* W1    = (const float*)d_in[9];
    const float* b1    = (const float*)d_in[10];
    const float* W2    = (const float*)d_in[11];
    const float* b2    = (const float*)d_in[12];
    const float* Wu    = (const float*)d_in[13];
    const float* bu    = (const float*)d_in[14];
    const float* Wout  = (const float*)d_in[15];
    const float* bout  = (const float*)d_in[16];

    k1_lstm<<<BATCH, 64, 0, stream>>>(sent, h0, c0, Wih_f, Whh_f, b_f,
                                      Wih_b, Whh_b, b_b);
    k2_proj<<<32, 256, 0, stream>>>(W1, b1, Wu, bu, Wout);
    k34_binary<<<1024, 256, 0, stream>>>(W2, b2, bout, (float*)d_out);
}

// Round 7
// 235.578 us; speedup vs baseline: 1.2615x; 1.0036x over previous
//
#include <hip/hip_runtime.h>
#include <hip/hip_bf16.h>
#include <math.h>

// Sizes (fixed by the problem)
#define BATCH 16
#define TLEN  512
#define HD    16     // per-direction hidden
#define HID   32     // 2*HD

typedef float v2f __attribute__((ext_vector_type(2)));
typedef unsigned u2v __attribute__((ext_vector_type(2)));

// Static device scratch — avoids any assumption about ws_size.
__device__ float g_outBT[BATCH * TLEN * HID];   // 1 MB
__device__ float g_preA [BATCH * TLEN * HID];   // 1 MB
__device__ float g_Ct   [BATCH * HID * TLEN];   // 1 MB
__device__ float g_un   [BATCH * TLEN];
__device__ float g_w2d  [BATCH * TLEN];
__device__ float g_accum[BATCH];                // zero-initialized, self-resetting
__device__ int   g_cnt  [BATCH];                // zero-initialized, self-resetting

__device__ __forceinline__ float sigm_(float x) {
    return 1.0f / (1.0f + __expf(-x));
}

__device__ __forceinline__ float ex2_(float x) {
#if __has_builtin(__builtin_amdgcn_exp2f)
    return __builtin_amdgcn_exp2f(x);     // raw v_exp_f32 (2^x)
#else
    return exp2f(x);
#endif
}
__device__ __forceinline__ float rcp_(float x) {
#if __has_builtin(__builtin_amdgcn_rcpf)
    return __builtin_amdgcn_rcpf(x);      // raw v_rcp_f32 — avoids IEEE div chain
#else
    return 1.0f / x;
#endif
}

__device__ __forceinline__ v2f pk_fma(v2f a, v2f b, v2f c) {
#if __has_builtin(__builtin_elementwise_fma)
    return __builtin_elementwise_fma(a, b, c);   // -> v_pk_fma_f32
#else
    v2f r; r.x = fmaf(a.x, b.x, c.x); r.y = fmaf(a.y, b.y, c.y); return r;
#endif
}

// ---------------------------------------------------------------------------
// K1: bidirectional LSTM, round 13 — force weight residency with an IN-LOOP pin.
// Round-12 post-mortem: VGPR_Count=36 < weight working set AGAIN (3rd
// structure in a row). The init-time asm pin only forces residency at that
// point; the compiler still sinks the weight loads into the t-loop, and each
// step eats ~one cache round-trip (~250 cyc) at the vmcnt wait before the dot
// (invisible in FETCH_SIZE — the re-reads are L1/L2 hits). Issue is only ~66
// cyc of a ~475-cyc step.
// Fix: empty `asm volatile` with ALL 18 weight v2fs as "+v" operands INSIDE
// the t-loop (once per 4-step chunk). Because the asm may-write them, the
// post-asm values are the asm's outputs — re-loading from memory inside the
// loop is now ILLEGAL, so the loads stay hoisted and the 36 VGPRs stay live
// across the backedge. Weights individually named: no array demotion path.
// Success signal: VGPR_Count >= ~70 and k1 ~55-70 us. If VGPR stays <= 40:
// hipcc spills around the asm -> next structure = LDS-resident weights.
// Math/structure otherwise identical to round 12 (passed, absmax=0).
// ---------------------------------------------------------------------------
__global__ __launch_bounds__(64, 1) void k1_lstm(
    const float* __restrict__ sent,   // [B,T]
    const float* __restrict__ h0,     // [2,B,16]
    const float* __restrict__ c0,     // [2,B,16]
    const float* __restrict__ Wih_f, const float* __restrict__ Whh_f, const float* __restrict__ b_f,
    const float* __restrict__ Wih_b, const float* __restrict__ Whh_b, const float* __restrict__ b_b)
{
    const int b    = blockIdx.x;       // 0..15
    const int lane = threadIdx.x;
    const int dir  = lane >> 5;        // 0 fwd (lanes 0-31), 1 bwd (32-63)
    const int ps   = (lane >> 4) & 1;  // 0 -> gates (i,f), 1 -> gates (g,o)
    const int u    = lane & 15;        // unit

    const float* Wih  = dir ? Wih_b : Wih_f;
    const float* Whh  = dir ? Whh_b : Whh_f;
    const float* bias = dir ? b_b   : b_f;

    const float L2E = 1.4426950408889634f;
    // exp-argument scales folded into weights: sigm uses 2^(-log2e*p),
    // tanh-gate uses 2^(2*log2e*p).
    const float sA = ps ? (2.0f * L2E) : (-L2E);  // gate g : gate i
    const float sB = -L2E;                        // gates f and o (sigm)
    const int gA = ps ? 2 : 0, gB = ps ? 3 : 1;   // torch order i,f,g,o
    const int rA = u + 16 * gA, rB = u + 16 * gB;

    // 16 packed recurrent weights, INDIVIDUALLY NAMED; wv<k> multiplies
    // h[(u-k)&15].
    v2f wv0, wv1, wv2, wv3, wv4, wv5, wv6, wv7,
        wv8, wv9, wv10, wv11, wv12, wv13, wv14, wv15;
#define LDW(K) { const int m = (u - (K)) & 15;       \
        wv##K.x = Whh[rA * 16 + m] * sA;             \
        wv##K.y = Whh[rB * 16 + m] * sB; }
    LDW(0)  LDW(1)  LDW(2)  LDW(3)  LDW(4)  LDW(5)  LDW(6)  LDW(7)
    LDW(8)  LDW(9)  LDW(10) LDW(11) LDW(12) LDW(13) LDW(14) LDW(15)
#undef LDW
    v2f wx2; wx2.x = Wih[rA] * sA;  wx2.y = Wih[rB] * sB;
    v2f bb2; bb2.x = bias[rA] * sA; bb2.y = bias[rB] * sB;
    // activation: act = fma(mm, rcp(2^p' + 1), aa)
    //  sigm gates: mm=1, aa=0.  gate g (emits 2log2e*tanh): mm=-4log2e, aa=2log2e
    v2f mm2; mm2.x = ps ? (-4.0f * L2E) : 1.0f; mm2.y = 1.0f;
    v2f aa2; aa2.x = ps ? ( 2.0f * L2E) : 0.0f; aa2.y = 0.0f;

    // replicated per-row state; c tracked scaled by 2*log2e
    float hn = h0[dir * (BATCH * HD) + b * HD + u];
    float cc = c0[dir * (BATCH * HD) + b * HD + u] * (2.0f * L2E);

    const float* srow = sent + b * TLEN;
    float* obase = g_outBT + (size_t)b * TLEN * HID + dir * HD + u;
    const int sg = dir ? -HID : HID;    // per-step store stride (elements)

    float4 xc = *(const float4*)(srow + (dir ? (TLEN - 4) : 0));
    for (int tb = 0; tb < TLEN; tb += 4) {
        // ---- THE PIN: weights may-be-written here every chunk -> the
        // compiler must keep them in VGPRs across the backedge; in-loop
        // re-loads are illegal.
        asm volatile("" :
            "+v"(wv0), "+v"(wv1), "+v"(wv2),  "+v"(wv3),
            "+v"(wv4), "+v"(wv5), "+v"(wv6),  "+v"(wv7),
            "+v"(wv8), "+v"(wv9), "+v"(wv10), "+v"(wv11),
            "+v"(wv12), "+v"(wv13), "+v"(wv14), "+v"(wv15),
            "+v"(wx2), "+v"(bb2));

        float4 xn = xc;
        if (tb + 4 < TLEN)
            xn = *(const float4*)(srow + (dir ? (TLEN - 8 - tb) : (tb + 4)));
        const float fx0 = xc.x, fx1 = xc.y, fx2 = xc.z, fx3 = xc.w;

        float hsave[4];

        #pragma unroll
        for (int s2 = 0; s2 < 4; ++s2) {
            // per-step x: fwd consumes s2, bwd consumes 3-s2 (reversed chunk)
            const float x = dir ? (s2 == 0 ? fx3 : s2 == 1 ? fx2 : s2 == 2 ? fx1 : fx0)
                                : (s2 == 0 ? fx0 : s2 == 1 ? fx1 : s2 == 2 ? fx2 : fx3);

            // 15 independent rotations of this row's h copy (literal DPP ctl)
            const int r0i = __float_as_int(hn);
            float rot[16];
            rot[0] = hn;
#define ROT(K) rot[K] = __int_as_float( \
                __builtin_amdgcn_mov_dpp(r0i, 0x120 + K, 0xF, 0xF, true));
            ROT(1)  ROT(2)  ROT(3)  ROT(4)  ROT(5)  ROT(6)  ROT(7)
            ROT(8)  ROT(9)  ROT(10) ROT(11) ROT(12) ROT(13) ROT(14) ROT(15)
#undef ROT

            // packed 16-term dot for both gates, 4 v2f accumulators
            v2f xv; xv.x = x; xv.y = x;
            v2f a0 = pk_fma(xv, wx2, bb2);
            v2f a1; a1.x = 0.f; a1.y = 0.f;
            v2f a2; a2.x = 0.f; a2.y = 0.f;
            v2f a3; a3.x = 0.f; a3.y = 0.f;
#define ACC(K, AV) { v2f hv; hv.x = rot[K]; hv.y = rot[K]; \
                     AV = pk_fma(wv##K, hv, AV); }
            ACC(0,  a0) ACC(1,  a1) ACC(2,  a2) ACC(3,  a3)
            ACC(4,  a0) ACC(5,  a1) ACC(6,  a2) ACC(7,  a3)
            ACC(8,  a0) ACC(9,  a1) ACC(10, a2) ACC(11, a3)
            ACC(12, a0) ACC(13, a1) ACC(14, a2) ACC(15, a3)
#undef ACC
            v2f p2 = (a0 + a1) + (a2 + a3);   // pre-acts, exp-scale folded in

            // activation: e = 2^p', inv = rcp(e+1), act = fma(mm, inv, aa)
            v2f ee;  ee.x  = ex2_(p2.x);        ee.y  = ex2_(p2.y);
            v2f iv;  iv.x  = rcp_(ee.x + 1.0f); iv.y  = rcp_(ee.y + 1.0f);
            v2f act = pk_fma(mm2, iv, aa2);
            // ps0 lanes: act = (ai, af).  ps1 lanes: act = (2log2e*tanh_g, ao)

            // partner gate pair via one swap per component (lane^16)
            float swx, swy;
            {
                const unsigned axi = (unsigned)__float_as_int(act.x);
                u2v qx = __builtin_amdgcn_permlane16_swap(axi, axi, false, false);
                swx = __int_as_float((int)(ps ? qx[0] : qx[1]));
                const unsigned ayi = (unsigned)__float_as_int(act.y);
                u2v qy = __builtin_amdgcn_permlane16_swap(ayi, ayi, false, false);
                swy = __int_as_float((int)(ps ? qy[0] : qy[1]));
            }
            const float ai = ps ? swx  : act.x;
            const float af = ps ? swy  : act.y;
            const float ag = ps ? act.x : swx;   // = 2log2e * tanh(p_g)
            const float ao = ps ? act.y : swy;

            // c' = af*c' + ai*(2log2e*tanh_g)   (c' = 2log2e * c)
            cc = fmaf(af, cc, ai * ag);
            // tanh(c) = 1 - 2/(2^c' + 1)
            const float e2   = ex2_(cc);
            const float inv2 = rcp_(e2 + 1.0f);
            const float z    = fmaf(-2.0f, inv2, 1.0f);
            hn = ao * z;
            hsave[s2] = hn;
        }

        // batched store: ps==0 rows (lanes 0-15 fwd, 32-47 bwd)
        if (ps == 0) {
            float* bp = obase + (size_t)(dir ? (TLEN - 1 - tb) : tb) * HID;
            bp[0]      = hsave[0];
            bp[sg]     = hsave[1];
            bp[2 * sg] = hsave[2];
            bp[3 * sg] = hsave[3];
        }
        xc = xn;
    }
}

// ---------------------------------------------------------------------------
// K2: projections. Thread per (b,t). W1 etc. staged in LDS.
// ---------------------------------------------------------------------------
__global__ __launch_bounds__(256) void k2_proj(
    const float* __restrict__ W1,     // [32,64]
    const float* __restrict__ b1,     // [32]
    const float* __restrict__ Wu,     // [32]
    const float* __restrict__ bu,     // [1]
    const float* __restrict__ Wout)   // [32]
{
    __shared__ float w1s[HID * 64];
    __shared__ float b1s[HID], wus[HID], wos[HID];
    const int tid = threadIdx.x;
    for (int k = tid; k < HID * 64; k += 256) w1s[k] = W1[k];
    if (tid < HID) { b1s[tid] = b1[tid]; wus[tid] = Wu[tid]; wos[tid] = Wout[tid]; }
    __syncthreads();

    const int g = blockIdx.x * 256 + tid;    // 0..8191
    const int b = g >> 9;
    const int t = g & (TLEN - 1);

    float o[32];
    const float4* src = (const float4*)(g_outBT + (size_t)g * HID);
    #pragma unroll
    for (int qq = 0; qq < 8; ++qq) {
        float4 v = src[qq];
        o[qq * 4 + 0] = v.x; o[qq * 4 + 1] = v.y; o[qq * 4 + 2] = v.z; o[qq * 4 + 3] = v.w;
    }

    float* pa = g_preA + (size_t)g * HID;
    float* ct = g_Ct + (size_t)b * HID * TLEN + t;
    #pragma unroll 4
    for (int h = 0; h < HID; ++h) {
        float a = b1s[h], cacc = 0.f;
        const float* wr = &w1s[h * 64];
        #pragma unroll
        for (int k = 0; k < HID; ++k) {
            a    = fmaf(o[k], wr[k], a);
            cacc = fmaf(o[k], wr[32 + k], cacc);
        }
        pa[h] = a;
        ct[(size_t)h * TLEN] = cacc;
    }

    float ua = 0.f, wa = 0.f;
    #pragma unroll
    for (int k = 0; k < HID; ++k) { ua = fmaf(o[k], wus[k], ua); wa = fmaf(o[k], wos[k], wa); }
    g_un[g]  = ua + bu[0];
    g_w2d[g] = wa;
}

// ---------------------------------------------------------------------------
// K34: S[b,i] = sum_j sum_h relu(preA[b,i,h] + Ct[b,h,j]) * W2[h]
//      prob[b,i] = sigmoid((S - diag_i + 511*b2)/100 + un[b,i])
//      out[b] = sum_i prob[b,i]*w2d[b,i] / 512 + bout
// ---------------------------------------------------------------------------
__global__ __launch_bounds__(256) void k34_binary(
    const float* __restrict__ W2,     // [32]
    const float* __restrict__ b2p,    // [1]
    const float* __restrict__ boutp,  // [1]
    float* __restrict__ out)          // [16]
{
    const int b     = blockIdx.x >> 6;
    const int itile = blockIdx.x & 63;
    const int i0    = itile * 8;
    const int tid   = threadIdx.x;

    __shared__ float pa[8][HID];
    __shared__ float w2s[HID];
    __shared__ float redw[4][8];

    pa[tid >> 5][tid & 31] = g_preA[((size_t)b * TLEN + i0 + (tid >> 5)) * HID + (tid & 31)];
    if (tid < HID) w2s[tid] = W2[tid];
    __syncthreads();

    const float* ctb = g_Ct + (size_t)b * HID * TLEN;
    const int j0 = tid, j1 = tid + 256;

    float acc[8];
    #pragma unroll
    for (int ii = 0; ii < 8; ++ii) acc[ii] = 0.f;

    #pragma unroll 8
    for (int h = 0; h < HID; ++h) {
        const float c0v = ctb[(size_t)h * TLEN + j0];
        const float c1v = ctb[(size_t)h * TLEN + j1];
        const float w   = w2s[h];
        #pragma unroll
        for (int ii = 0; ii < 8; ++ii) {
            const float p = pa[ii][h];
            acc[ii] = fmaf(fmaxf(p + c0v, 0.f), w, acc[ii]);
            acc[ii] = fmaf(fmaxf(p + c1v, 0.f), w, acc[ii]);
        }
    }

    #pragma unroll
    for (int ii = 0; ii < 8; ++ii) {
        float v = acc[ii];
        #pragma unroll
        for (int off = 32; off >= 1; off >>= 1) v += __shfl_down(v, off);
        if ((tid & 63) == 0) redw[tid >> 6][ii] = v;
    }
    __syncthreads();

    if (tid < 8) {
        const float S = redw[0][tid] + redw[1][tid] + redw[2][tid] + redw[3][tid];
        const int i = i0 + tid;
        float diag = 0.f;
        #pragma unroll
        for (int h = 0; h < HID; ++h)
            diag = fmaf(fmaxf(pa[tid][h] + ctb[(size_t)h * TLEN + i], 0.f), w2s[h], diag);
        const float b2 = b2p[0];
        const float s = (S - diag + (float)(TLEN - 1) * b2) * 0.01f + g_un[(size_t)b * TLEN + i];
        float contrib = sigm_(s) * g_w2d[(size_t)b * TLEN + i];
        contrib += __shfl_down(contrib, 4);
        contrib += __shfl_down(contrib, 2);
        contrib += __shfl_down(contrib, 1);
        if (tid == 0) {
            atomicAdd(&g_accum[b], contrib);
            __threadfence();
            int old = atomicAdd(&g_cnt[b], 1);
            if (old == 63) {
                __threadfence();
                float tot = atomicExch(&g_accum[b], 0.0f);
                out[b] = tot * (1.0f / (float)TLEN) + boutp[0];
                atomicExch(&g_cnt[b], 0);
            }
        }
    }
}

extern "C" void kernel_launch(void* const* d_in, const int* in_sizes, int n_in,
                              void* d_out, int out_size, void* d_ws, size_t ws_size,
                              hipStream_t stream) {
    const float* sent  = (const float*)d_in[0];
    const float* h0    = (const float*)d_in[1];
    const float* c0    = (const float*)d_in[2];
    const float* Wih_f = (const float*)d_in[3];
    const float* Whh_f = (const float*)d_in[4];
    const float* b_f   = (const float*)d_in[5];
    const float* Wih_b = (const float*)d_in[6];
    const float* Whh_b = (const float*)d_in[7];
    const float* b_b   = (const float*)d_in[8];
    const float* W1    = (const float*)d_in[9];
    const float* b1    = (const float*)d_in[10];
    const float* W2    = (const float*)d_in[11];
    const float* b2    = (const float*)d_in[12];
    const float* Wu    = (const float*)d_in[13];
    const float* bu    = (const float*)d_in[14];
    const float* Wout  = (const float*)d_in[15];
    const float* bout  = (const float*)d_in[16];

    k1_lstm<<<BATCH, 64, 0, stream>>>(sent, h0, c0, Wih_f, Whh_f, b_f,
                                      Wih_b, Whh_b, b_b);
    k2_proj<<<32, 256, 0, stream>>>(W1, b1, Wu, bu, Wout);
    k34_binary<<<1024, 256, 0, stream>>>(W2, b2, bout, (float*)d_out);
}

// Round 8
// 215.437 us; speedup vs baseline: 1.3794x; 1.0935x over previous
//
#include <hip/hip_runtime.h>
#include <hip/hip_bf16.h>
#include <math.h>

// Sizes (fixed by the problem)
#define BATCH 16
#define TLEN  512
#define HD    16     // per-direction hidden
#define HID   32     // 2*HD

typedef float v2f __attribute__((ext_vector_type(2)));
typedef unsigned u2v __attribute__((ext_vector_type(2)));

// Static device scratch — avoids any assumption about ws_size.
__device__ float g_outBT[BATCH * TLEN * HID];   // 1 MB
__device__ float g_preA [BATCH * TLEN * HID];   // 1 MB
__device__ float g_Ct   [BATCH * HID * TLEN];   // 1 MB
__device__ float g_un   [BATCH * TLEN];
__device__ float g_w2d  [BATCH * TLEN];
__device__ float g_accum[BATCH];                // zero-initialized, self-resetting
__device__ int   g_cnt  [BATCH];                // zero-initialized, self-resetting

__device__ __forceinline__ float sigm_(float x) {
    return 1.0f / (1.0f + __expf(-x));
}

__device__ __forceinline__ float ex2_(float x) {
#if __has_builtin(__builtin_amdgcn_exp2f)
    return __builtin_amdgcn_exp2f(x);     // raw v_exp_f32 (2^x)
#else
    return exp2f(x);
#endif
}
__device__ __forceinline__ float rcp_(float x) {
#if __has_builtin(__builtin_amdgcn_rcpf)
    return __builtin_amdgcn_rcpf(x);      // raw v_rcp_f32 — avoids IEEE div chain
#else
    return 1.0f / x;
#endif
}

// ---------------------------------------------------------------------------
// K1: bidirectional LSTM, round 14 — merge the two verified structures.
// Round-7 post-mortem: in-loop register pin was NEUTRAL (VGPR 36, dur 101 us
// unchanged) -> weights were ALREADY resident; the "re-fetch" theory is dead.
// Recount of the round-12 stream: v_pk_fma_f32 is HALF-RATE for f32 (spec:
// packed doesn't raise the 157-TF f32 peak), so the packed dot costs 64 cyc
// VALU vs 32 cyc for the same MACs as scalar fma in a 1-chain/wave layout.
// The active SIMD is ~40-55% VALU-busy: the step is about half issue-bound.
// This round = round-11 layout (1 chain/wave: 32 blocks, lane r = gate row,
// g=r>>4, u=r&15; dir is WAVE-UNIFORM so the x path is scalar) + round-12
// math (folded exp2 scales, raw v_rcp, c tracked scaled by 2*log2e), which
// was never applied to this layout. Extras: per-step x-base fmas hoisted to
// chunk top (off the serial chain), chunk = 8 steps, batched stores.
// Gate gather = round-11-verified 3x permlane16/32_swap + select ladder.
// ---------------------------------------------------------------------------
__global__ __launch_bounds__(64, 1) void k1_lstm(
    const float* __restrict__ sent,   // [B,T]
    const float* __restrict__ h0,     // [2,B,16]
    const float* __restrict__ c0,     // [2,B,16]
    const float* __restrict__ Wih_f, const float* __restrict__ Whh_f, const float* __restrict__ b_f,
    const float* __restrict__ Wih_b, const float* __restrict__ Whh_b, const float* __restrict__ b_b)
{
    const int blk = blockIdx.x;       // 0..31
    const int dir = blk >> 4;         // 0 fwd, 1 bwd (wave-uniform)
    const int b   = blk & 15;         // batch
    const int r   = threadIdx.x;      // gate row 0..63
    const int u   = r & 15;           // unit
    const int g   = r >> 4;           // 0=i,1=f,2=g,3=o

    const float* Wih  = dir ? Wih_b : Wih_f;
    const float* Whh  = dir ? Whh_b : Whh_f;
    const float* bias = dir ? b_b   : b_f;

    const float L2E = 1.4426950408889634f;
    // fold the exp2 argument scale into this gate row's weights:
    //   sigm rows (i,f,o): p' = -log2e * p  -> sigm(p) = rcp(2^p' + 1)
    //   tanh row  (g):     p' = 2*log2e * p -> tanh(p) = 1 - 2*rcp(2^p' + 1)
    const bool  isg = (g == 2);
    const float sc  = isg ? (2.0f * L2E) : (-L2E);
    // act = fma(mm, rcp(2^p' + 1), aa); g row emits 2log2e*tanh directly.
    const float mm  = isg ? (-4.0f * L2E) : 1.0f;
    const float aa  = isg ? ( 2.0f * L2E) : 0.0f;

    // 16 scalar recurrent weights; wh<k> multiplies h[(u-k)&15].
    float wh0, wh1, wh2, wh3, wh4, wh5, wh6, wh7,
          wh8, wh9, wh10, wh11, wh12, wh13, wh14, wh15;
#define LDW(K) { const int m = (u - (K)) & 15; wh##K = Whh[r * 16 + m] * sc; }
    LDW(0)  LDW(1)  LDW(2)  LDW(3)  LDW(4)  LDW(5)  LDW(6)  LDW(7)
    LDW(8)  LDW(9)  LDW(10) LDW(11) LDW(12) LDW(13) LDW(14) LDW(15)
#undef LDW
    const float wx = Wih[r] * sc;
    const float bb = bias[r] * sc;

    const bool gb0 = (g & 1) != 0;
    const bool gb1 = (g & 2) != 0;

    // replicated per-row state: h[u], and c[u] scaled by 2*log2e
    float hn = h0[dir * (BATCH * HD) + b * HD + u];
    float cc = c0[dir * (BATCH * HD) + b * HD + u] * (2.0f * L2E);

    const float* srow = sent + b * TLEN;
    float* obase = g_outBT + (size_t)b * TLEN * HID + dir * HD + u;
    const int sg = dir ? -HID : HID;    // per-step store stride (elements)

    // 8-step chunks, double-buffered x (two float4 per chunk)
    float4 xcA = *(const float4*)(srow + (dir ? (TLEN - 8) : 0));
    float4 xcB = *(const float4*)(srow + (dir ? (TLEN - 4) : 4));
    for (int tb = 0; tb < TLEN; tb += 8) {
        float4 xnA = xcA, xnB = xcB;
        if (tb + 8 < TLEN) {
            const int nb = dir ? (TLEN - 16 - tb) : (tb + 8);
            xnA = *(const float4*)(srow + nb);
            xnB = *(const float4*)(srow + nb + 4);
        }
        // chunk-order x values (bwd consumes the chunk reversed)
        float xs[8];
        if (dir) {
            xs[0] = xcB.w; xs[1] = xcB.z; xs[2] = xcB.y; xs[3] = xcB.x;
            xs[4] = xcA.w; xs[5] = xcA.z; xs[6] = xcA.y; xs[7] = xcA.x;
        } else {
            xs[0] = xcA.x; xs[1] = xcA.y; xs[2] = xcA.z; xs[3] = xcA.w;
            xs[4] = xcB.x; xs[5] = xcB.y; xs[6] = xcB.z; xs[7] = xcB.w;
        }
        // hoisted x-base: independent of the recurrence, off the serial chain
        float pb[8];
        #pragma unroll
        for (int s2 = 0; s2 < 8; ++s2) pb[s2] = fmaf(xs[s2], wx, bb);

        float hsave[8];

        #pragma unroll
        for (int s2 = 0; s2 < 8; ++s2) {
            // 15 independent rotations of this row's h copy (literal DPP ctl)
            const int r0i = __float_as_int(hn);
            float rot[16];
            rot[0] = hn;
#define ROT(K) rot[K] = __int_as_float( \
                __builtin_amdgcn_mov_dpp(r0i, 0x120 + K, 0xF, 0xF, true));
            ROT(1)  ROT(2)  ROT(3)  ROT(4)  ROT(5)  ROT(6)  ROT(7)
            ROT(8)  ROT(9)  ROT(10) ROT(11) ROT(12) ROT(13) ROT(14) ROT(15)
#undef ROT

            // 16-term scalar dot, 4 accumulators (dep depth 4 + 2 add levels)
            float a0 = fmaf(rot[0], wh0,  pb[s2]);
            float a1 = rot[1] * wh1;
            float a2 = rot[2] * wh2;
            float a3 = rot[3] * wh3;
            a0 = fmaf(rot[4],  wh4,  a0);
            a1 = fmaf(rot[5],  wh5,  a1);
            a2 = fmaf(rot[6],  wh6,  a2);
            a3 = fmaf(rot[7],  wh7,  a3);
            a0 = fmaf(rot[8],  wh8,  a0);
            a1 = fmaf(rot[9],  wh9,  a1);
            a2 = fmaf(rot[10], wh10, a2);
            a3 = fmaf(rot[11], wh11, a3);
            a0 = fmaf(rot[12], wh12, a0);
            a1 = fmaf(rot[13], wh13, a1);
            a2 = fmaf(rot[14], wh14, a2);
            a3 = fmaf(rot[15], wh15, a3);
            const float p = (a0 + a1) + (a2 + a3);   // pre-act, scale folded

            // activation: act = fma(mm, rcp(2^p + 1), aa)
            const float e   = ex2_(p);
            const float iv  = rcp_(e + 1.0f);
            const float act = fmaf(mm, iv, aa);
            // i/f/o rows: sigm(p).  g row: 2log2e * tanh(p).

            // gather the other three gate rows' activations (VALU permlane)
            float x1, x2, x3;
            {
                const unsigned ai_ = (unsigned)__float_as_int(act);
                u2v q16 = __builtin_amdgcn_permlane16_swap(ai_, ai_, false, false);
                x1 = __int_as_float((int)(gb0 ? q16[0] : q16[1]));
                u2v q32 = __builtin_amdgcn_permlane32_swap(ai_, ai_, false, false);
                const unsigned x2i = gb1 ? q32[0] : q32[1];
                x2 = __int_as_float((int)x2i);
                u2v q48 = __builtin_amdgcn_permlane16_swap(x2i, x2i, false, false);
                x3 = __int_as_float((int)(gb0 ? q48[0] : q48[1]));
            }

            // X[s] = act of row g^s; role j needs X[g^j]  (round-10 verified)
            const float lo_i = gb0 ? x1  : act;
            const float hi_i = gb0 ? x3  : x2;
            const float ai   = gb1 ? hi_i : lo_i;     // X[g]   = sigm_i
            const float lo_f = gb0 ? act : x1;
            const float hi_f = gb0 ? x2  : x3;
            const float af   = gb1 ? hi_f : lo_f;     // X[g^1] = sigm_f
            const float lo_g = gb0 ? x1  : act;
            const float hi_g = gb0 ? x3  : x2;
            const float ag   = gb1 ? lo_g : hi_g;     // X[g^2] = 2log2e*tanh_g
            const float lo_o = gb0 ? act : x1;
            const float hi_o = gb0 ? x2  : x3;
            const float ao   = gb1 ? lo_o : hi_o;     // X[g^3] = sigm_o

            // c' = af*c' + ai*(2log2e*tanh_g)   (c' = 2log2e * c)
            cc = fmaf(af, cc, ai * ag);
            // tanh(c) = 1 - 2*rcp(2^c' + 1)  (overflow-safe: E=inf -> z=1)
            const float e2   = ex2_(cc);
            const float inv2 = rcp_(e2 + 1.0f);
            const float z    = fmaf(-2.0f, inv2, 1.0f);
            hn = ao * z;
            hsave[s2] = hn;
        }

        // batched store: g==0 rows (16 lanes), one exec toggle per 8 steps
        if (g == 0) {
            float* bp = obase + (size_t)(dir ? (TLEN - 1 - tb) : tb) * HID;
            #pragma unroll
            for (int s2 = 0; s2 < 8; ++s2) bp[s2 * sg] = hsave[s2];
        }
        xcA = xnA; xcB = xnB;
    }
}

// ---------------------------------------------------------------------------
// K2: projections. Thread per (b,t). W1 etc. staged in LDS.
// ---------------------------------------------------------------------------
__global__ __launch_bounds__(256) void k2_proj(
    const float* __restrict__ W1,     // [32,64]
    const float* __restrict__ b1,     // [32]
    const float* __restrict__ Wu,     // [32]
    const float* __restrict__ bu,     // [1]
    const float* __restrict__ Wout)   // [32]
{
    __shared__ float w1s[HID * 64];
    __shared__ float b1s[HID], wus[HID], wos[HID];
    const int tid = threadIdx.x;
    for (int k = tid; k < HID * 64; k += 256) w1s[k] = W1[k];
    if (tid < HID) { b1s[tid] = b1[tid]; wus[tid] = Wu[tid]; wos[tid] = Wout[tid]; }
    __syncthreads();

    const int g = blockIdx.x * 256 + tid;    // 0..8191
    const int b = g >> 9;
    const int t = g & (TLEN - 1);

    float o[32];
    const float4* src = (const float4*)(g_outBT + (size_t)g * HID);
    #pragma unroll
    for (int qq = 0; qq < 8; ++qq) {
        float4 v = src[qq];
        o[qq * 4 + 0] = v.x; o[qq * 4 + 1] = v.y; o[qq * 4 + 2] = v.z; o[qq * 4 + 3] = v.w;
    }

    float* pa = g_preA + (size_t)g * HID;
    float* ct = g_Ct + (size_t)b * HID * TLEN + t;
    #pragma unroll 4
    for (int h = 0; h < HID; ++h) {
        float a = b1s[h], cacc = 0.f;
        const float* wr = &w1s[h * 64];
        #pragma unroll
        for (int k = 0; k < HID; ++k) {
            a    = fmaf(o[k], wr[k], a);
            cacc = fmaf(o[k], wr[32 + k], cacc);
        }
        pa[h] = a;
        ct[(size_t)h * TLEN] = cacc;
    }

    float ua = 0.f, wa = 0.f;
    #pragma unroll
    for (int k = 0; k < HID; ++k) { ua = fmaf(o[k], wus[k], ua); wa = fmaf(o[k], wos[k], wa); }
    g_un[g]  = ua + bu[0];
    g_w2d[g] = wa;
}

// ---------------------------------------------------------------------------
// K34: S[b,i] = sum_j sum_h relu(preA[b,i,h] + Ct[b,h,j]) * W2[h]
//      prob[b,i] = sigmoid((S - diag_i + 511*b2)/100 + un[b,i])
//      out[b] = sum_i prob[b,i]*w2d[b,i] / 512 + bout
// ---------------------------------------------------------------------------
__global__ __launch_bounds__(256) void k34_binary(
    const float* __restrict__ W2,     // [32]
    const float* __restrict__ b2p,    // [1]
    const float* __restrict__ boutp,  // [1]
    float* __restrict__ out)          // [16]
{
    const int b     = blockIdx.x >> 6;
    const int itile = blockIdx.x & 63;
    const int i0    = itile * 8;
    const int tid   = threadIdx.x;

    __shared__ float pa[8][HID];
    __shared__ float w2s[HID];
    __shared__ float redw[4][8];

    pa[tid >> 5][tid & 31] = g_preA[((size_t)b * TLEN + i0 + (tid >> 5)) * HID + (tid & 31)];
    if (tid < HID) w2s[tid] = W2[tid];
    __syncthreads();

    const float* ctb = g_Ct + (size_t)b * HID * TLEN;
    const int j0 = tid, j1 = tid + 256;

    float acc[8];
    #pragma unroll
    for (int ii = 0; ii < 8; ++ii) acc[ii] = 0.f;

    #pragma unroll 8
    for (int h = 0; h < HID; ++h) {
        const float c0v = ctb[(size_t)h * TLEN + j0];
        const float c1v = ctb[(size_t)h * TLEN + j1];
        const float w   = w2s[h];
        #pragma unroll
        for (int ii = 0; ii < 8; ++ii) {
            const float p = pa[ii][h];
            acc[ii] = fmaf(fmaxf(p + c0v, 0.f), w, acc[ii]);
            acc[ii] = fmaf(fmaxf(p + c1v, 0.f), w, acc[ii]);
        }
    }

    #pragma unroll
    for (int ii = 0; ii < 8; ++ii) {
        float v = acc[ii];
        #pragma unroll
        for (int off = 32; off >= 1; off >>= 1) v += __shfl_down(v, off);
        if ((tid & 63) == 0) redw[tid >> 6][ii] = v;
    }
    __syncthreads();

    if (tid < 8) {
        const float S = redw[0][tid] + redw[1][tid] + redw[2][tid] + redw[3][tid];
        const int i = i0 + tid;
        float diag = 0.f;
        #pragma unroll
        for (int h = 0; h < HID; ++h)
            diag = fmaf(fmaxf(pa[tid][h] + ctb[(size_t)h * TLEN + i], 0.f), w2s[h], diag);
        const float b2 = b2p[0];
        const float s = (S - diag + (float)(TLEN - 1) * b2) * 0.01f + g_un[(size_t)b * TLEN + i];
        float contrib = sigm_(s) * g_w2d[(size_t)b * TLEN + i];
        contrib += __shfl_down(contrib, 4);
        contrib += __shfl_down(contrib, 2);
        contrib += __shfl_down(contrib, 1);
        if (tid == 0) {
            atomicAdd(&g_accum[b], contrib);
            __threadfence();
            int old = atomicAdd(&g_cnt[b], 1);
            if (old == 63) {
                __threadfence();
                float tot = atomicExch(&g_accum[b], 0.0f);
                out[b] = tot * (1.0f / (float)TLEN) + boutp[0];
                atomicExch(&g_cnt[b], 0);
            }
        }
    }
}

extern "C" void kernel_launch(void* const* d_in, const int* in_sizes, int n_in,
                              void* d_out, int out_size, void* d_ws, size_t ws_size,
                              hipStream_t stream) {
    const float* sent  = (const float*)d_in[0];
    const float* h0    = (const float*)d_in[1];
    const float* c0    = (const float*)d_in[2];
    const float* Wih_f = (const float*)d_in[3];
    const float* Whh_f = (const float*)d_in[4];
    const float* b_f   = (const float*)d_in[5];
    const float* Wih_b = (const float*)d_in[6];
    const float* Whh_b = (const float*)d_in[7];
    const float* b_b   = (const float*)d_in[8];
    const float* W1    = (const float*)d_in[9];
    const float* b1    = (const float*)d_in[10];
    const float* W2    = (const float*)d_in[11];
    const float* b2    = (const float*)d_in[12];
    const float* Wu    = (const float*)d_in[13];
    const float* bu    = (const float*)d_in[14];
    const float* Wout  = (const float*)d_in[15];
    const float* bout  = (const float*)d_in[16];

    k1_lstm<<<32, 64, 0, stream>>>(sent, h0, c0, Wih_f, Whh_f, b_f,
                                   Wih_b, Whh_b, b_b);
    k2_proj<<<32, 256, 0, stream>>>(W1, b1, Wu, bu, Wout);
    k34_binary<<<1024, 256, 0, stream>>>(W2, b2, bout, (float*)d_out);
}